// Round 1
// baseline (2163.304 us; speedup 1.0000x reference)
//
#include <hip/hip_runtime.h>
#include <hip/hip_bf16.h>

#define GG 5000
#define BB 128
#define HH 64
#define EE 100000
#define RR (BB*GG)      // 640000 rows
#define NT (RR/64)      // 10000 tiles of 64 rows
#define EPS 1e-5f

__device__ __forceinline__ float dot4(const float4 a, const float4 b, float acc) {
  acc = fmaf(a.x, b.x, acc);
  acc = fmaf(a.y, b.y, acc);
  acc = fmaf(a.z, b.z, acc);
  acc = fmaf(a.w, b.w, acc);
  return acc;
}

// ---------- small kernels ----------

// row-renorm to norm<=1 (nn.Embedding max_norm=1 semantics). one wave per row.
__global__ void renorm_rows(const float* __restrict__ X, float* __restrict__ out, int nrows) {
  int wid = threadIdx.x >> 6, lane = threadIdx.x & 63;
  int i = blockIdx.x * 4 + wid;
  if (i >= nrows) return;
  float v = X[i * HH + lane];
  float s = v * v;
  #pragma unroll
  for (int m = 1; m < 64; m <<= 1) s += __shfl_xor(s, m);
  float n = sqrtf(s);
  float scale = fminf(1.f, 1.f / fmaxf(n, 1e-12f));
  out[i * HH + lane] = v * scale;
}

// per-column mean/biased-var of X [nrows,64]; one block per column.
__global__ void colstats(const float* __restrict__ X, int nrows,
                         float* __restrict__ mean, float* __restrict__ var) {
  int c = blockIdx.x;
  float s = 0.f, q = 0.f;
  for (int r = threadIdx.x; r < nrows; r += 256) {
    float v = X[r * HH + c];
    s += v; q += v * v;
  }
  __shared__ float ls[256], lq[256];
  ls[threadIdx.x] = s; lq[threadIdx.x] = q;
  __syncthreads();
  for (int o = 128; o > 0; o >>= 1) {
    if (threadIdx.x < o) { ls[threadIdx.x] += ls[threadIdx.x + o]; lq[threadIdx.x] += lq[threadIdx.x + o]; }
    __syncthreads();
  }
  if (threadIdx.x == 0) {
    float m = ls[0] / (float)nrows;
    mean[c] = m;
    var[c] = lq[0] / (float)nrows - m * m;
  }
}

// a = gamma*rsqrt(var+eps); b = beta - mean*a
__global__ void make_affine(const float* __restrict__ gamma, const float* __restrict__ beta,
                            const float* __restrict__ mean, const float* __restrict__ var,
                            float* __restrict__ a, float* __restrict__ b, int n) {
  int i = threadIdx.x;
  if (i < n) {
    float av = gamma[i] * rsqrtf(fmaxf(var[i], 0.f) + EPS);
    a[i] = av;
    b[i] = beta[i] - mean[i] * av;
  }
}

// out = (relu?) (a[col]*X + b[col]) elementwise over [N,64]
__global__ void apply_affine(const float* __restrict__ X, const float* __restrict__ a,
                             const float* __restrict__ b, float* __restrict__ out,
                             int total, int relu) {
  int i = blockIdx.x * 256 + threadIdx.x;
  if (i >= total) return;
  int c = i & 63;
  float v = fmaf(a[c], X[i], b[c]);
  out[i] = relu ? fmaxf(v, 0.f) : v;
}

// BN affine from accumulated sums: var = Q/n - (S/n)^2
__global__ void finish_bn(const float* __restrict__ S, const float* __restrict__ Q,
                          const float* __restrict__ gamma, const float* __restrict__ beta,
                          float* __restrict__ a, float* __restrict__ bc, int n, float inv_count) {
  int j = threadIdx.x;
  if (j < n) {
    float m = S[j] * inv_count;
    float v = Q[j] * inv_count - m * m;
    float av = gamma[j] * rsqrtf(fmaxf(v, 0.f) + EPS);
    a[j] = av;
    bc[j] = beta[j] - m * av;
  }
}

// bnp stats decomposition: z = base[g,h]+fused[b,h] -> mean=mb+mf, var=vb+vf (exact)
__global__ void make_bnp(const float* __restrict__ mb, const float* __restrict__ vb,
                         const float* __restrict__ mf, const float* __restrict__ vf,
                         const float* __restrict__ g, const float* __restrict__ bt,
                         float* __restrict__ az, float* __restrict__ bz) {
  int h = threadIdx.x;
  if (h < HH) {
    float a = g[h] * rsqrtf(vb[h] + vf[h] + EPS);
    az[h] = a;
    bz[h] = bt[h] - (mb[h] + mf[h]) * a;
  }
}

// SGConv pieces
__global__ void edge_deg(const int* __restrict__ dst, const float* __restrict__ ew,
                         float* __restrict__ deg) {
  int e = blockIdx.x * 256 + threadIdx.x;
  if (e < EE) atomicAdd(&deg[dst[e]], ew[e]);
}
__global__ void finish_dis(float* __restrict__ deg) {
  int i = blockIdx.x * 256 + threadIdx.x;
  if (i < GG) deg[i] = rsqrtf(deg[i] + 1.0f);  // +1 self-loop; always >0
}
__global__ void agg_init(const float* __restrict__ dis, const float* __restrict__ rnp,
                         float* __restrict__ agg) {
  int idx = blockIdx.x * 256 + threadIdx.x;
  if (idx < GG * HH) {
    int i = idx >> 6;
    float d = dis[i];
    agg[idx] = d * d * rnp[idx];  // self-loop: dis*1*dis
  }
}
__global__ void agg_edges(const int* __restrict__ src, const int* __restrict__ dst,
                          const float* __restrict__ ew, const float* __restrict__ dis,
                          const float* __restrict__ rnp, float* __restrict__ agg) {
  int idx = blockIdx.x * 256 + threadIdx.x;
  int e = idx >> 6, h = idx & 63;
  if (e < EE) {
    int s = src[e], d = dst[e];
    float c = dis[s] * ew[e] * dis[d];
    atomicAdd(&agg[d * HH + h], c * rnp[s * HH + h]);
  }
}

// out[i,j] = sum_h X[i,h]*W[j,h] + bias[j], X [N,64], W [M,64] row-major, M<=64
__global__ void gemm_rows64(const float* __restrict__ X, const float* __restrict__ W,
                            const float* __restrict__ bias, float* __restrict__ out,
                            int N, int M) {
  __shared__ float sx[4][HH];
  int wid = threadIdx.x >> 6, lane = threadIdx.x & 63;
  int i = blockIdx.x * 4 + wid;
  if (i < N) sx[wid][lane] = X[i * HH + lane];
  __syncthreads();
  if (i >= N) return;
  for (int j = lane; j < M; j += 64) {
    float acc = bias[j];
    const float* wr = W + j * HH;
    #pragma unroll 16
    for (int h = 0; h < HH; ++h) acc = fmaf(sx[wid][h], wr[h], acc);
    out[i * M + j] = acc;
  }
}

// psum[b,j] = sum_g pert[b,g]*pge[g,j]; one block per b
__global__ void psum_kernel(const int* __restrict__ pert, const float* __restrict__ pge,
                            float* __restrict__ out) {
  int b = blockIdx.x;
  int j = threadIdx.x & 63, part = threadIdx.x >> 6;
  float acc = 0.f;
  for (int g = part; g < GG; g += 4)
    acc = fmaf((float)pert[b * GG + g], pge[g * HH + j], acc);
  __shared__ float ls[256];
  ls[threadIdx.x] = acc;
  __syncthreads();
  if (part == 0) out[b * HH + j] = ls[j] + ls[j + 64] + ls[j + 128] + ls[j + 192];
}

// cross layer 1: out[b,j] = sum_g w[b,g]*Wc[j,g] + bias[j]   (Wc = c_W1 [64,5000])
__global__ void cross1_kernel(const float* __restrict__ wv, const float* __restrict__ Wc,
                              const float* __restrict__ bias, float* __restrict__ out) {
  int b = blockIdx.x;
  int j = threadIdx.x & 63, part = threadIdx.x >> 6;
  float acc = 0.f;
  for (int g = part; g < GG; g += 4)
    acc = fmaf(wv[b * GG + g], Wc[j * GG + g], acc);
  __shared__ float ls[256];
  ls[threadIdx.x] = acc;
  __syncthreads();
  if (part == 0) out[b * HH + j] = bias[j] + ls[j] + ls[j + 64] + ls[j + 128] + ls[j + 192];
}

// final: out[b,g] = w*iw2[g,0] + sum_h cross[b,h]*iw2[g,1+h] + ib2[g] + expr
__global__ void final_kernel(const float* __restrict__ wv, const float* __restrict__ cross,
                             const float* __restrict__ iw2, const float* __restrict__ ib2,
                             const float* __restrict__ expr, float* __restrict__ out) {
  __shared__ float cs[HH];
  int b = blockIdx.y;
  int g = blockIdx.x * 256 + threadIdx.x;
  if (threadIdx.x < HH) cs[threadIdx.x] = cross[b * HH + threadIdx.x];
  __syncthreads();
  if (g >= GG) return;
  const float* r = iw2 + g * 65;
  float acc = fmaf(wv[b * GG + g], r[0], ib2[g] + expr[b * GG + g]);
  #pragma unroll 16
  for (int h = 0; h < HH; ++h) acc = fmaf(cs[h], r[1 + h], acc);
  out[b * GG + g] = acc;
}

// ---------- big fused kernels over R=640K rows ----------
// MODE 0: y1 = z@W1^T + b1, accumulate column sum/sumsq -> S1,Q1
// MODE 1: recompute y1 -> t=relu(a1*y1+b1c) -> y2 = t@W2^T + b2, accumulate S2,Q2
// MODE 2: full recompute -> out=a2*y2+b2c -> w[r] = sum_n out*iw1[g,n] + ib1[g]
template <int MODE>
__global__ __launch_bounds__(512)
void big_kernel(const float* __restrict__ base, const float* __restrict__ fused,
                const float* __restrict__ az, const float* __restrict__ bz,
                const float* __restrict__ W1, const float* __restrict__ b1,
                const float* __restrict__ W2, const float* __restrict__ b2,
                const float* __restrict__ a1, const float* __restrict__ b1c,
                const float* __restrict__ a2, const float* __restrict__ b2c,
                const float* __restrict__ iw1, const float* __restrict__ ib1,
                float* __restrict__ S1, float* __restrict__ Q1,
                float* __restrict__ S2, float* __restrict__ Q2,
                float* __restrict__ w_out) {
  // LDS: z tile 64x64 (float4-swizzled), W1 [128][68], optionally t tile 64x128 + W2 [64][132]
  __shared__ float4 zs[64 * 16];
  __shared__ float w1s[128 * 68];
  __shared__ float s_az[HH], s_bz[HH];
  __shared__ float4 ts[(MODE > 0) ? 64 * 32 : 1];
  __shared__ float w2s[(MODE > 0) ? 64 * 132 : 1];
  __shared__ float wsum[(MODE == 2) ? 64 : 1];

  const int tid = threadIdx.x;
  const int wid = tid >> 6;          // 0..7
  const int lane = tid & 63;
  const int rg = lane & 15;          // row group: rows {rg, rg+16, rg+32, rg+48}
  const int quad = lane >> 4;        // 0..3
  const int jg = wid * 4 + quad;     // 0..31 : GEMM1 j-group (4 cols), GEMM2 n-pair group

  // stage weights
  for (int idx = tid; idx < 128 * 64; idx += 512) {
    int j = idx >> 6, k = idx & 63;
    w1s[j * 68 + k] = W1[idx];
  }
  if (MODE > 0) {
    for (int idx = tid; idx < 64 * 128; idx += 512) {
      int n = idx >> 7, j = idx & 127;
      w2s[n * 132 + j] = W2[idx];
    }
  }
  if (tid < HH) { s_az[tid] = az[tid]; s_bz[tid] = bz[tid]; }

  // per-thread constants
  const float4 bias1 = *(const float4*)(&b1[jg * 4]);
  float4 a1v = make_float4(0, 0, 0, 0), b1v = make_float4(0, 0, 0, 0);
  float b2v0 = 0, b2v1 = 0, a2v0 = 0, a2v1 = 0, c2v0 = 0, c2v1 = 0;
  if (MODE > 0) {
    a1v = *(const float4*)(&a1[jg * 4]);
    b1v = *(const float4*)(&b1c[jg * 4]);
    b2v0 = b2[2 * jg]; b2v1 = b2[2 * jg + 1];
  }
  if (MODE == 2) {
    a2v0 = a2[2 * jg]; a2v1 = a2[2 * jg + 1];
    c2v0 = b2c[2 * jg]; c2v1 = b2c[2 * jg + 1];
  }

  float ss[4] = {0, 0, 0, 0}, qq[4] = {0, 0, 0, 0};     // MODE0 stats
  float ss2[2] = {0, 0}, qq2[2] = {0, 0};               // MODE1 stats

  for (int tile = blockIdx.x; tile < NT; tile += gridDim.x) {
    __syncthreads();  // previous tile's LDS reads done
    const int r0 = tile * 64;

    // phase A: z tile -> LDS (swizzled float4 slots)
    #pragma unroll
    for (int it = 0; it < 2; ++it) {
      int idx = tid + it * 512;           // 0..1023
      int row = idx >> 4, slot = idx & 15;
      int r = r0 + row;
      int b = r / GG;
      int g = r - b * GG;
      const float4 bs = *(const float4*)(&base[g * HH + slot * 4]);
      const float4 fs = *(const float4*)(&fused[b * HH + slot * 4]);
      int h = slot * 4;
      float4 v;
      v.x = fmaxf(fmaf(s_az[h + 0], bs.x + fs.x, s_bz[h + 0]), 0.f);
      v.y = fmaxf(fmaf(s_az[h + 1], bs.y + fs.y, s_bz[h + 1]), 0.f);
      v.z = fmaxf(fmaf(s_az[h + 2], bs.z + fs.z, s_bz[h + 2]), 0.f);
      v.w = fmaxf(fmaf(s_az[h + 3], bs.w + fs.w, s_bz[h + 3]), 0.f);
      zs[row * 16 + (slot ^ (row & 15))] = v;
    }
    __syncthreads();

    // GEMM1: y1[rows, jg*4..+3]
    float acc[4][4];
    #pragma unroll
    for (int i = 0; i < 4; ++i)
      #pragma unroll
      for (int jj = 0; jj < 4; ++jj) acc[i][jj] = 0.f;
    #pragma unroll 8
    for (int k4 = 0; k4 < 16; ++k4) {
      const int sw = k4 ^ rg;
      float4 zr[4];
      #pragma unroll
      for (int i = 0; i < 4; ++i) zr[i] = zs[(rg + 16 * i) * 16 + sw];
      #pragma unroll
      for (int jj = 0; jj < 4; ++jj) {
        const float4 wvv = *(const float4*)(&w1s[(jg * 4 + jj) * 68 + k4 * 4]);
        #pragma unroll
        for (int i = 0; i < 4; ++i) acc[i][jj] = dot4(zr[i], wvv, acc[i][jj]);
      }
    }
    const float bb1[4] = {bias1.x, bias1.y, bias1.z, bias1.w};
    const float aa1[4] = {a1v.x, a1v.y, a1v.z, a1v.w};
    const float cc1[4] = {b1v.x, b1v.y, b1v.z, b1v.w};
    float tval[4][4];
    #pragma unroll
    for (int i = 0; i < 4; ++i) {
      #pragma unroll
      for (int jj = 0; jj < 4; ++jj) {
        float y = acc[i][jj] + bb1[jj];
        if (MODE == 0) { ss[jj] += y; qq[jj] += y * y; }
        else tval[i][jj] = fmaxf(fmaf(aa1[jj], y, cc1[jj]), 0.f);
      }
    }

    if (MODE > 0) {
      #pragma unroll
      for (int i = 0; i < 4; ++i)
        ts[(rg + 16 * i) * 32 + (jg ^ rg)] = make_float4(tval[i][0], tval[i][1], tval[i][2], tval[i][3]);
      __syncthreads();

      // GEMM2: y2[rows, 2*jg..+1]
      float acc2[4][2];
      #pragma unroll
      for (int i = 0; i < 4; ++i) { acc2[i][0] = 0.f; acc2[i][1] = 0.f; }
      #pragma unroll 8
      for (int k4 = 0; k4 < 32; ++k4) {
        const int sw = k4 ^ rg;
        float4 tr[4];
        #pragma unroll
        for (int i = 0; i < 4; ++i) tr[i] = ts[(rg + 16 * i) * 32 + sw];
        #pragma unroll
        for (int c = 0; c < 2; ++c) {
          const float4 wvv = *(const float4*)(&w2s[(2 * jg + c) * 132 + k4 * 4]);
          #pragma unroll
          for (int i = 0; i < 4; ++i) acc2[i][c] = dot4(tr[i], wvv, acc2[i][c]);
        }
      }

      if (MODE == 1) {
        #pragma unroll
        for (int i = 0; i < 4; ++i) {
          float y20 = acc2[i][0] + b2v0;
          float y21 = acc2[i][1] + b2v1;
          ss2[0] += y20; qq2[0] += y20 * y20;
          ss2[1] += y21; qq2[1] += y21 * y21;
        }
      } else {  // MODE 2
        float part[4];
        #pragma unroll
        for (int i = 0; i < 4; ++i) {
          float y20 = acc2[i][0] + b2v0;
          float y21 = acc2[i][1] + b2v1;
          float o0 = fmaf(a2v0, y20, c2v0);
          float o1 = fmaf(a2v1, y21, c2v1);
          int r = r0 + rg + 16 * i;
          int g = r - (r / GG) * GG;
          const float2 wv2 = *(const float2*)(&iw1[g * HH + 2 * jg]);
          part[i] = o0 * wv2.x + o1 * wv2.y;
        }
        __syncthreads();
        if (tid < 64) wsum[tid] = 0.f;
        __syncthreads();
        #pragma unroll
        for (int i = 0; i < 4; ++i) atomicAdd(&wsum[rg + 16 * i], part[i]);
        __syncthreads();
        if (tid < 64) {
          int r = r0 + tid;
          int g = r - (r / GG) * GG;
          w_out[r] = wsum[tid] + ib1[g];
        }
      }
    }
  }

  // flush stats (lanes sharing a column are the 16-lane groups; reduce low 4 lane bits)
  if (MODE == 0) {
    #pragma unroll
    for (int m = 1; m < 16; m <<= 1) {
      #pragma unroll
      for (int jj = 0; jj < 4; ++jj) {
        ss[jj] += __shfl_xor(ss[jj], m);
        qq[jj] += __shfl_xor(qq[jj], m);
      }
    }
    if (rg == 0) {
      #pragma unroll
      for (int jj = 0; jj < 4; ++jj) {
        atomicAdd(&S1[jg * 4 + jj], ss[jj]);
        atomicAdd(&Q1[jg * 4 + jj], qq[jj]);
      }
    }
  }
  if (MODE == 1) {
    #pragma unroll
    for (int m = 1; m < 16; m <<= 1) {
      #pragma unroll
      for (int c = 0; c < 2; ++c) {
        ss2[c] += __shfl_xor(ss2[c], m);
        qq2[c] += __shfl_xor(qq2[c], m);
      }
    }
    if (rg == 0) {
      atomicAdd(&S2[2 * jg], ss2[0]);
      atomicAdd(&S2[2 * jg + 1], ss2[1]);
      atomicAdd(&Q2[2 * jg], qq2[0]);
      atomicAdd(&Q2[2 * jg + 1], qq2[1]);
    }
  }
}

// ---------- launcher ----------

extern "C" void kernel_launch(void* const* d_in, const int* in_sizes, int n_in,
                              void* d_out, int out_size, void* d_ws, size_t ws_size,
                              hipStream_t stream) {
  const float* expr     = (const float*)d_in[0];
  const int*   pert     = (const int*)d_in[1];
  const int*   ei       = (const int*)d_in[2];
  const float* ew       = (const float*)d_in[3];
  const float* gene_emb = (const float*)d_in[4];
  const float* pert_emb = (const float*)d_in[5];
  const float* bn_emb_g = (const float*)d_in[6];
  const float* bn_emb_b = (const float*)d_in[7];
  const float* sg_W     = (const float*)d_in[8];
  const float* sg_b     = (const float*)d_in[9];
  const float* pf_W1    = (const float*)d_in[10];
  const float* pf_b1    = (const float*)d_in[11];
  const float* pf_g1    = (const float*)d_in[12];
  const float* pf_be1   = (const float*)d_in[13];
  const float* pf_W2    = (const float*)d_in[14];
  const float* pf_b2    = (const float*)d_in[15];
  const float* pf_g2    = (const float*)d_in[16];
  const float* pf_be2   = (const float*)d_in[17];
  const float* bnp_g    = (const float*)d_in[18];
  const float* bnp_b    = (const float*)d_in[19];
  const float* r_W1     = (const float*)d_in[20];
  const float* r_b1     = (const float*)d_in[21];
  const float* r_g1     = (const float*)d_in[22];
  const float* r_be1    = (const float*)d_in[23];
  const float* r_W2     = (const float*)d_in[24];
  const float* r_b2     = (const float*)d_in[25];
  const float* r_g2     = (const float*)d_in[26];
  const float* r_be2    = (const float*)d_in[27];
  const float* iw1      = (const float*)d_in[28];
  const float* ib1      = (const float*)d_in[29];
  const float* c_W1     = (const float*)d_in[30];
  const float* c_b1     = (const float*)d_in[31];
  const float* c_g1     = (const float*)d_in[32];
  const float* c_be1    = (const float*)d_in[33];
  const float* c_W2     = (const float*)d_in[34];
  const float* c_b2     = (const float*)d_in[35];
  const float* c_g2     = (const float*)d_in[36];
  const float* c_be2    = (const float*)d_in[37];
  const float* iw2      = (const float*)d_in[38];
  const float* ib2      = (const float*)d_in[39];
  float* out = (float*)d_out;
  float* ws = (float*)d_ws;

  // ws layout (floats), total ~1.96M floats = 7.9 MB
  float* base = ws + 0;        // [G,H] renormed gene_emb, then relu(BN(.)) in place
  float* rnp  = ws + 320000;   // [G,H] renormed pert_emb
  float* agg  = ws + 640000;   // [G,H]
  float* pge  = ws + 960000;   // [G,H]
  float* wv   = ws + 1280000;  // [B,G] per-gene scalar head
  float* dis  = ws + 1920000;  // [G] deg -> rsqrt
  float* psum = ws + 1925120;  // [B,H]
  float* fusd = ws + 1933312;  // [B,H]
  float* tmpA = ws + 1941504;  // [B,H]
  float* crs  = ws + 1949696;  // [B,H]
  float* mtmp = ws + 1957888;
  float* vtmp = ws + 1958016;
  float* affa = ws + 1958144;
  float* affb = ws + 1958272;
  float* mb   = ws + 1958400;
  float* vb_  = ws + 1958464;
  float* mf   = ws + 1958528;
  float* vf   = ws + 1958592;
  float* az   = ws + 1958656;
  float* bz   = ws + 1958720;
  float* S1   = ws + 1958784;  // [128]
  float* Q1   = ws + 1958912;  // [128]
  float* S2   = ws + 1959040;  // [64]
  float* Q2   = ws + 1959104;  // [64]
  float* a1   = ws + 1959168;  // [128]
  float* b1c  = ws + 1959296;  // [128]
  float* a2   = ws + 1959424;  // [64]
  float* b2c  = ws + 1959488;  // [64]

  const int* src = ei;
  const int* dst = ei + EE;

  // --- gene embedding path: renorm -> BN -> relu -> base; stats of base for bnp
  renorm_rows<<<(GG + 3) / 4, 256, 0, stream>>>(gene_emb, base, GG);
  colstats<<<HH, 256, 0, stream>>>(base, GG, mtmp, vtmp);
  make_affine<<<1, 128, 0, stream>>>(bn_emb_g, bn_emb_b, mtmp, vtmp, affa, affb, HH);
  apply_affine<<<(GG * HH + 255) / 256, 256, 0, stream>>>(base, affa, affb, base, GG * HH, 1);
  colstats<<<HH, 256, 0, stream>>>(base, GG, mb, vb_);

  // --- SGConv path
  renorm_rows<<<(GG + 3) / 4, 256, 0, stream>>>(pert_emb, rnp, GG);
  hipMemsetAsync(dis, 0, GG * sizeof(float), stream);
  edge_deg<<<(EE + 255) / 256, 256, 0, stream>>>(dst, ew, dis);
  finish_dis<<<(GG + 255) / 256, 256, 0, stream>>>(dis);
  agg_init<<<(GG * HH + 255) / 256, 256, 0, stream>>>(dis, rnp, agg);
  agg_edges<<<(EE * 64 + 255) / 256, 256, 0, stream>>>(src, dst, ew, dis, rnp, agg);
  gemm_rows64<<<(GG + 3) / 4, 256, 0, stream>>>(agg, sg_W, sg_b, pge, GG, HH);
  psum_kernel<<<BB, 256, 0, stream>>>(pert, pge, psum);

  // --- pert_fuse MLP: Lin-BN-ReLU-Lin-BN on [B,H]
  gemm_rows64<<<(BB + 3) / 4, 256, 0, stream>>>(psum, pf_W1, pf_b1, tmpA, BB, HH);
  colstats<<<HH, 256, 0, stream>>>(tmpA, BB, mtmp, vtmp);
  make_affine<<<1, 128, 0, stream>>>(pf_g1, pf_be1, mtmp, vtmp, affa, affb, HH);
  apply_affine<<<(BB * HH + 255) / 256, 256, 0, stream>>>(tmpA, affa, affb, tmpA, BB * HH, 1);
  gemm_rows64<<<(BB + 3) / 4, 256, 0, stream>>>(tmpA, pf_W2, pf_b2, fusd, BB, HH);
  colstats<<<HH, 256, 0, stream>>>(fusd, BB, mtmp, vtmp);
  make_affine<<<1, 128, 0, stream>>>(pf_g2, pf_be2, mtmp, vtmp, affa, affb, HH);
  apply_affine<<<(BB * HH + 255) / 256, 256, 0, stream>>>(fusd, affa, affb, fusd, BB * HH, 0);
  colstats<<<HH, 256, 0, stream>>>(fusd, BB, mf, vf);
  make_bnp<<<1, 64, 0, stream>>>(mb, vb_, mf, vf, bnp_g, bnp_b, az, bz);

  // --- recovery MLP over 640K rows (3 passes)
  hipMemsetAsync(S1, 0, 384 * sizeof(float), stream);  // S1,Q1,S2,Q2 contiguous
  big_kernel<0><<<2048, 512, 0, stream>>>(base, fusd, az, bz, r_W1, r_b1, r_W2, r_b2,
                                          a1, b1c, a2, b2c, iw1, ib1, S1, Q1, S2, Q2, wv);
  finish_bn<<<1, 128, 0, stream>>>(S1, Q1, r_g1, r_be1, a1, b1c, 128, 1.0f / (float)RR);
  big_kernel<1><<<2048, 512, 0, stream>>>(base, fusd, az, bz, r_W1, r_b1, r_W2, r_b2,
                                          a1, b1c, a2, b2c, iw1, ib1, S1, Q1, S2, Q2, wv);
  finish_bn<<<1, 128, 0, stream>>>(S2, Q2, r_g2, r_be2, a2, b2c, 64, 1.0f / (float)RR);
  big_kernel<2><<<2048, 512, 0, stream>>>(base, fusd, az, bz, r_W1, r_b1, r_W2, r_b2,
                                          a1, b1c, a2, b2c, iw1, ib1, S1, Q1, S2, Q2, wv);

  // --- cross_gene_state MLP: [B,G]->H->H with BNs
  cross1_kernel<<<BB, 256, 0, stream>>>(wv, c_W1, c_b1, tmpA);
  colstats<<<HH, 256, 0, stream>>>(tmpA, BB, mtmp, vtmp);
  make_affine<<<1, 128, 0, stream>>>(c_g1, c_be1, mtmp, vtmp, affa, affb, HH);
  apply_affine<<<(BB * HH + 255) / 256, 256, 0, stream>>>(tmpA, affa, affb, tmpA, BB * HH, 1);
  gemm_rows64<<<(BB + 3) / 4, 256, 0, stream>>>(tmpA, c_W2, c_b2, crs, BB, HH);
  colstats<<<HH, 256, 0, stream>>>(crs, BB, mtmp, vtmp);
  make_affine<<<1, 128, 0, stream>>>(c_g2, c_be2, mtmp, vtmp, affa, affb, HH);
  apply_affine<<<(BB * HH + 255) / 256, 256, 0, stream>>>(crs, affa, affb, crs, BB * HH, 0);

  // --- final per-gene head + residual
  final_kernel<<<dim3((GG + 255) / 256, BB), 256, 0, stream>>>(wv, crs, iw2, ib2, expr, out);
}

// Round 3
// 1004.361 us; speedup vs baseline: 2.1539x; 2.1539x over previous
//
#include <hip/hip_runtime.h>
#include <hip/hip_bf16.h>

#define GG 5000
#define BB 128
#define HH 64
#define EE 100000
#define RR (BB*GG)      // 640000 rows
#define NT (RR/64)      // 10000 tiles of 64 rows
#define EPS 1e-5f

typedef __attribute__((ext_vector_type(8))) short short8;
typedef __attribute__((ext_vector_type(4))) float f32x4;

__device__ __forceinline__ float dot4(const float4 a, const float4 b, float acc) {
  acc = fmaf(a.x, b.x, acc);
  acc = fmaf(a.y, b.y, acc);
  acc = fmaf(a.z, b.z, acc);
  acc = fmaf(a.w, b.w, acc);
  return acc;
}

__device__ __forceinline__ ushort f2b(float f) {
  union { float f; unsigned int u; } c; c.f = f;
  unsigned int u = c.u;
  return (ushort)((u + 0x7FFFu + ((u >> 16) & 1u)) >> 16);
}

// ---------- small kernels ----------

__global__ void renorm_rows(const float* __restrict__ X, float* __restrict__ out, int nrows) {
  int wid = threadIdx.x >> 6, lane = threadIdx.x & 63;
  int i = blockIdx.x * 4 + wid;
  if (i >= nrows) return;
  float v = X[i * HH + lane];
  float s = v * v;
  #pragma unroll
  for (int m = 1; m < 64; m <<= 1) s += __shfl_xor(s, m);
  float n = sqrtf(s);
  float scale = fminf(1.f, 1.f / fmaxf(n, 1e-12f));
  out[i * HH + lane] = v * scale;
}

__global__ void colstats(const float* __restrict__ X, int nrows,
                         float* __restrict__ mean, float* __restrict__ var) {
  int c = blockIdx.x;
  float s = 0.f, q = 0.f;
  for (int r = threadIdx.x; r < nrows; r += 256) {
    float v = X[r * HH + c];
    s += v; q += v * v;
  }
  __shared__ float ls[256], lq[256];
  ls[threadIdx.x] = s; lq[threadIdx.x] = q;
  __syncthreads();
  for (int o = 128; o > 0; o >>= 1) {
    if (threadIdx.x < o) { ls[threadIdx.x] += ls[threadIdx.x + o]; lq[threadIdx.x] += lq[threadIdx.x + o]; }
    __syncthreads();
  }
  if (threadIdx.x == 0) {
    float m = ls[0] / (float)nrows;
    mean[c] = m;
    var[c] = lq[0] / (float)nrows - m * m;
  }
}

__global__ void make_affine(const float* __restrict__ gamma, const float* __restrict__ beta,
                            const float* __restrict__ mean, const float* __restrict__ var,
                            float* __restrict__ a, float* __restrict__ b, int n) {
  int i = threadIdx.x;
  if (i < n) {
    float av = gamma[i] * rsqrtf(fmaxf(var[i], 0.f) + EPS);
    a[i] = av;
    b[i] = beta[i] - mean[i] * av;
  }
}

__global__ void apply_affine(const float* __restrict__ X, const float* __restrict__ a,
                             const float* __restrict__ b, float* __restrict__ out,
                             int total, int relu) {
  int i = blockIdx.x * 256 + threadIdx.x;
  if (i >= total) return;
  int c = i & 63;
  float v = fmaf(a[c], X[i], b[c]);
  out[i] = relu ? fmaxf(v, 0.f) : v;
}

__global__ void finish_bn(const float* __restrict__ S, const float* __restrict__ Q,
                          const float* __restrict__ gamma, const float* __restrict__ beta,
                          float* __restrict__ a, float* __restrict__ bc, int n, float inv_count) {
  int j = threadIdx.x;
  if (j < n) {
    float m = S[j] * inv_count;
    float v = Q[j] * inv_count - m * m;
    float av = gamma[j] * rsqrtf(fmaxf(v, 0.f) + EPS);
    a[j] = av;
    bc[j] = beta[j] - m * av;
  }
}

__global__ void make_bnp(const float* __restrict__ mb, const float* __restrict__ vb,
                         const float* __restrict__ mf, const float* __restrict__ vf,
                         const float* __restrict__ g, const float* __restrict__ bt,
                         float* __restrict__ az, float* __restrict__ bz) {
  int h = threadIdx.x;
  if (h < HH) {
    float a = g[h] * rsqrtf(vb[h] + vf[h] + EPS);
    az[h] = a;
    bz[h] = bt[h] - (mb[h] + mf[h]) * a;
  }
}

__global__ void edge_deg(const int* __restrict__ dst, const float* __restrict__ ew,
                         float* __restrict__ deg) {
  int e = blockIdx.x * 256 + threadIdx.x;
  if (e < EE) atomicAdd(&deg[dst[e]], ew[e]);
}
__global__ void finish_dis(float* __restrict__ deg) {
  int i = blockIdx.x * 256 + threadIdx.x;
  if (i < GG) deg[i] = rsqrtf(deg[i] + 1.0f);
}
__global__ void agg_init(const float* __restrict__ dis, const float* __restrict__ rnp,
                         float* __restrict__ agg) {
  int idx = blockIdx.x * 256 + threadIdx.x;
  if (idx < GG * HH) {
    int i = idx >> 6;
    float d = dis[i];
    agg[idx] = d * d * rnp[idx];
  }
}
__global__ void agg_edges(const int* __restrict__ src, const int* __restrict__ dst,
                          const float* __restrict__ ew, const float* __restrict__ dis,
                          const float* __restrict__ rnp, float* __restrict__ agg) {
  int idx = blockIdx.x * 256 + threadIdx.x;
  int e = idx >> 6, h = idx & 63;
  if (e < EE) {
    int s = src[e], d = dst[e];
    float c = dis[s] * ew[e] * dis[d];
    atomicAdd(&agg[d * HH + h], c * rnp[s * HH + h]);
  }
}

__global__ void gemm_rows64(const float* __restrict__ X, const float* __restrict__ W,
                            const float* __restrict__ bias, float* __restrict__ out,
                            int N, int M) {
  __shared__ float sx[4][HH];
  int wid = threadIdx.x >> 6, lane = threadIdx.x & 63;
  int i = blockIdx.x * 4 + wid;
  if (i < N) sx[wid][lane] = X[i * HH + lane];
  __syncthreads();
  if (i >= N) return;
  for (int j = lane; j < M; j += 64) {
    float acc = bias[j];
    const float* wr = W + j * HH;
    #pragma unroll 16
    for (int h = 0; h < HH; ++h) acc = fmaf(sx[wid][h], wr[h], acc);
    out[i * M + j] = acc;
  }
}

__global__ void psum_kernel(const int* __restrict__ pert, const float* __restrict__ pge,
                            float* __restrict__ out) {
  int b = blockIdx.x;
  int j = threadIdx.x & 63, part = threadIdx.x >> 6;
  float acc = 0.f;
  for (int g = part; g < GG; g += 4)
    acc = fmaf((float)pert[b * GG + g], pge[g * HH + j], acc);
  __shared__ float ls[256];
  ls[threadIdx.x] = acc;
  __syncthreads();
  if (part == 0) out[b * HH + j] = ls[j] + ls[j + 64] + ls[j + 128] + ls[j + 192];
}

__global__ void cross1_kernel(const float* __restrict__ wv, const float* __restrict__ Wc,
                              const float* __restrict__ bias, float* __restrict__ out) {
  int b = blockIdx.x;
  int j = threadIdx.x & 63, part = threadIdx.x >> 6;
  float acc = 0.f;
  for (int g = part; g < GG; g += 4)
    acc = fmaf(wv[b * GG + g], Wc[j * GG + g], acc);
  __shared__ float ls[256];
  ls[threadIdx.x] = acc;
  __syncthreads();
  if (part == 0) out[b * HH + j] = bias[j] + ls[j] + ls[j + 64] + ls[j + 128] + ls[j + 192];
}

__global__ void final_kernel(const float* __restrict__ wv, const float* __restrict__ cross,
                             const float* __restrict__ iw2, const float* __restrict__ ib2,
                             const float* __restrict__ expr, float* __restrict__ out) {
  __shared__ float cs[HH];
  int b = blockIdx.y;
  int g = blockIdx.x * 256 + threadIdx.x;
  if (threadIdx.x < HH) cs[threadIdx.x] = cross[b * HH + threadIdx.x];
  __syncthreads();
  if (g >= GG) return;
  const float* r = iw2 + g * 65;
  float acc = fmaf(wv[b * GG + g], r[0], ib2[g] + expr[b * GG + g]);
  #pragma unroll 16
  for (int h = 0; h < HH; ++h) acc = fmaf(cs[h], r[1 + h], acc);
  out[b * GG + g] = acc;
}

// ---------- MFMA big kernel over R=640K rows ----------
// MODE 0: y1 = z@W1^T + b1, accumulate column sum/sumsq -> S1,Q1
// MODE 1: recompute -> t=relu(a1*y1+b1c) -> y2 = t@W2^T + b2, accumulate S2,Q2
// MODE 2: full recompute -> out=a2*y2+b2c -> w[r] = sum_n out*iw1[g,n] + ib1[g]

template <int MODE>
__global__ __launch_bounds__(256, 3)
void big_kernel(const float* __restrict__ base, const float* __restrict__ fused,
                const float* __restrict__ az, const float* __restrict__ bz,
                const float* __restrict__ W1, const float* __restrict__ b1,
                const float* __restrict__ W2, const float* __restrict__ b2,
                const float* __restrict__ a1, const float* __restrict__ b1c,
                const float* __restrict__ a2, const float* __restrict__ b2c,
                const float* __restrict__ iw1, const float* __restrict__ ib1,
                float* __restrict__ S1, float* __restrict__ Q1,
                float* __restrict__ S2, float* __restrict__ Q2,
                float* __restrict__ w_out) {
  constexpr int SMEMB = (MODE == 0) ? 16384 : (MODE == 1) ? 32768 : 43008;
  __shared__ __align__(16) char sm[SMEMB];
  char* smz = sm;                      // [64][64] bf16, 8 KB  (steady)
  char* smt = sm + 8192;               // [64][128] bf16, 16 KB (MODE>0)
  float* smiw = (float*)(sm + 24576);  // [64][68] f32 (MODE2)
  float* smwp = (float*)(sm + 41984);  // [4][64] f32 (MODE2)
  // staging overlay (used once before main loop):
  char* smw1 = sm;                     // [128][64] bf16, 16 KB
  char* smw2 = sm + 16384;             // [64][128] bf16, 16 KB (MODE>0)

  const int tid = threadIdx.x;
  const int wid = tid >> 6;        // 0..3
  const int lane = tid & 63;
  const int l15 = lane & 15;
  const int l4 = lane >> 4;        // 0..3
  const int s = tid & 7;           // z-stage slot (stable across stage iters)

  // ---- stage W1 (and W2) as swizzled bf16 ----
  // W1 is [128][64] = 1024 slots of 8 floats -> 4 iterations of 256 threads.
  #pragma unroll
  for (int it = 0; it < 4; ++it) {
    int sid = tid + it * 256;          // 0..1023
    int j = sid >> 3, sl = sid & 7;
    const float4 lo = *(const float4*)(&W1[j * 64 + sl * 8]);
    const float4 hi = *(const float4*)(&W1[j * 64 + sl * 8 + 4]);
    union { short8 v; ushort u[8]; } pk;
    pk.u[0] = f2b(lo.x); pk.u[1] = f2b(lo.y); pk.u[2] = f2b(lo.z); pk.u[3] = f2b(lo.w);
    pk.u[4] = f2b(hi.x); pk.u[5] = f2b(hi.y); pk.u[6] = f2b(hi.z); pk.u[7] = f2b(hi.w);
    *(short8*)(smw1 + j * 128 + ((sl ^ (j & 7)) << 4)) = pk.v;
  }
  if (MODE > 0) {
    #pragma unroll
    for (int it = 0; it < 4; ++it) {
      int sid = tid + it * 256;        // 0..1023
      int n = sid >> 4, sl = sid & 15;
      const float4 lo = *(const float4*)(&W2[n * 128 + sl * 8]);
      const float4 hi = *(const float4*)(&W2[n * 128 + sl * 8 + 4]);
      union { short8 v; ushort u[8]; } pk;
      pk.u[0] = f2b(lo.x); pk.u[1] = f2b(lo.y); pk.u[2] = f2b(lo.z); pk.u[3] = f2b(lo.w);
      pk.u[4] = f2b(hi.x); pk.u[5] = f2b(hi.y); pk.u[6] = f2b(hi.z); pk.u[7] = f2b(hi.w);
      *(short8*)(smw2 + n * 256 + ((sl ^ (n & 15)) << 4)) = pk.v;
    }
  }
  __syncthreads();

  // ---- hoist W fragments into registers ----
  short8 b1f[2][2];   // [jt][ks]; col j = wid*32 + jt*16 + l15, k = l4*8 + 32*ks
  #pragma unroll
  for (int jt = 0; jt < 2; ++jt)
    #pragma unroll
    for (int ks = 0; ks < 2; ++ks) {
      int j = wid * 32 + jt * 16 + l15;
      b1f[jt][ks] = *(short8*)(smw1 + j * 128 + (((l4 + 4 * ks) ^ (l15 & 7)) << 4));
    }
  short8 b2f[4];      // [ks]; col n = wid*16 + l15, k = l4*8 + 32*ks
  if (MODE > 0) {
    #pragma unroll
    for (int ks = 0; ks < 4; ++ks) {
      int n = wid * 16 + l15;
      b2f[ks] = *(short8*)(smw2 + n * 256 + (((l4 + 4 * ks) ^ l15) << 4));
    }
  }
  __syncthreads();   // staging region now reusable as z/t

  // ---- per-thread constants ----
  const float4 azv0 = *(const float4*)(&az[s * 8]);
  const float4 azv1 = *(const float4*)(&az[s * 8 + 4]);
  const float4 bzv0 = *(const float4*)(&bz[s * 8]);
  const float4 bzv1 = *(const float4*)(&bz[s * 8 + 4]);
  float b1v[2], a1v[2], c1v[2];
  #pragma unroll
  for (int jt = 0; jt < 2; ++jt) {
    int j = wid * 32 + jt * 16 + l15;
    b1v[jt] = b1[j];
    if (MODE > 0) { a1v[jt] = a1[j]; c1v[jt] = b1c[j]; }
    else { a1v[jt] = 0.f; c1v[jt] = 0.f; }
  }
  const int nn = wid * 16 + l15;
  float b2v = 0, a2v = 0, c2v = 0;
  if (MODE > 0) b2v = b2[nn];
  if (MODE == 2) { a2v = a2[nn]; c2v = b2c[nn]; }

  float ss[2] = {0, 0}, qq[2] = {0, 0};   // MODE0
  float s2a = 0, q2a = 0;                 // MODE1

  for (int tile = blockIdx.x; tile < NT; tile += gridDim.x) {
    const int r0 = tile * 64;
    const int b0 = r0 / GG;
    const int g0 = r0 - b0 * GG;
    const int rem = GG - g0;   // rows before g wraps (tile wraps at most once)

    // ---- stage z tile (affine+relu+bf16, swizzled) ----
    #pragma unroll
    for (int it = 0; it < 2; ++it) {
      int sid = tid + it * 256;
      int rloc = sid >> 3;
      int g = g0 + rloc, bb = b0;
      if (rloc >= rem) { g -= GG; bb++; }
      const float4 x0 = *(const float4*)(&base[g * 64 + s * 8]);
      const float4 x1 = *(const float4*)(&base[g * 64 + s * 8 + 4]);
      const float4 f0 = *(const float4*)(&fused[bb * 64 + s * 8]);
      const float4 f1 = *(const float4*)(&fused[bb * 64 + s * 8 + 4]);
      union { short8 v; ushort u[8]; } pk;
      pk.u[0] = f2b(fmaxf(fmaf(azv0.x, x0.x + f0.x, bzv0.x), 0.f));
      pk.u[1] = f2b(fmaxf(fmaf(azv0.y, x0.y + f0.y, bzv0.y), 0.f));
      pk.u[2] = f2b(fmaxf(fmaf(azv0.z, x0.z + f0.z, bzv0.z), 0.f));
      pk.u[3] = f2b(fmaxf(fmaf(azv0.w, x0.w + f0.w, bzv0.w), 0.f));
      pk.u[4] = f2b(fmaxf(fmaf(azv1.x, x1.x + f1.x, bzv1.x), 0.f));
      pk.u[5] = f2b(fmaxf(fmaf(azv1.y, x1.y + f1.y, bzv1.y), 0.f));
      pk.u[6] = f2b(fmaxf(fmaf(azv1.z, x1.z + f1.z, bzv1.z), 0.f));
      pk.u[7] = f2b(fmaxf(fmaf(azv1.w, x1.w + f1.w, bzv1.w), 0.f));
      *(short8*)(smz + rloc * 128 + ((s ^ (rloc & 7)) << 4)) = pk.v;
    }
    if (MODE == 2) {
      // stage iw1 tile [64][68] f32
      int rloc = tid >> 2, c0 = (tid & 3) * 16;
      int g = g0 + rloc; if (rloc >= rem) g -= GG;
      #pragma unroll
      for (int i = 0; i < 4; ++i)
        *(float4*)(&smiw[rloc * 68 + c0 + 4 * i]) = *(const float4*)(&iw1[g * 64 + c0 + 4 * i]);
    }
    __syncthreads();   // (A)

    // ---- GEMM1: D1[rt][jt] ----
    f32x4 d1[4][2];
    #pragma unroll
    for (int rt = 0; rt < 4; ++rt)
      #pragma unroll
      for (int jt = 0; jt < 2; ++jt) d1[rt][jt] = (f32x4){0.f, 0.f, 0.f, 0.f};
    #pragma unroll
    for (int ks = 0; ks < 2; ++ks) {
      short8 af[4];
      #pragma unroll
      for (int rt = 0; rt < 4; ++rt) {
        int r = 16 * rt + l15;
        af[rt] = *(short8*)(smz + r * 128 + (((l4 + 4 * ks) ^ (l15 & 7)) << 4));
      }
      #pragma unroll
      for (int jt = 0; jt < 2; ++jt)
        #pragma unroll
        for (int rt = 0; rt < 4; ++rt)
          d1[rt][jt] = __builtin_amdgcn_mfma_f32_16x16x32_bf16(af[rt], b1f[jt][ks], d1[rt][jt], 0, 0, 0);
    }

    if (MODE == 0) {
      #pragma unroll
      for (int rt = 0; rt < 4; ++rt)
        #pragma unroll
        for (int jt = 0; jt < 2; ++jt)
          #pragma unroll
          for (int reg = 0; reg < 4; ++reg) {
            float y = d1[rt][jt][reg] + b1v[jt];
            ss[jt] += y; qq[jt] += y * y;
          }
      __syncthreads();   // guard next z-stage vs this GEMM1's reads
    } else {
      // ---- epilogue1: t = relu(a1*y1+b1c) -> LDS bf16 (swizzled) ----
      #pragma unroll
      for (int rt = 0; rt < 4; ++rt)
        #pragma unroll
        for (int jt = 0; jt < 2; ++jt) {
          int j = wid * 32 + jt * 16 + l15;
          int jhi = j >> 3, jlo = j & 7;
          #pragma unroll
          for (int reg = 0; reg < 4; ++reg) {
            int r = 16 * rt + l4 * 4 + reg;
            float y = d1[rt][jt][reg] + b1v[jt];
            float tv = fmaxf(fmaf(a1v[jt], y, c1v[jt]), 0.f);
            *(ushort*)(smt + r * 256 + ((jhi ^ (r & 15)) << 4) + jlo * 2) = f2b(tv);
          }
        }
      __syncthreads();   // (B)

      // ---- GEMM2: D2[rt], cols n = wid*16+l15 ----
      f32x4 d2[4];
      #pragma unroll
      for (int rt = 0; rt < 4; ++rt) d2[rt] = (f32x4){0.f, 0.f, 0.f, 0.f};
      #pragma unroll
      for (int ks = 0; ks < 4; ++ks) {
        short8 af[4];
        #pragma unroll
        for (int rt = 0; rt < 4; ++rt) {
          int r = 16 * rt + l15;
          af[rt] = *(short8*)(smt + r * 256 + (((l4 + 4 * ks) ^ l15) << 4));
        }
        #pragma unroll
        for (int rt = 0; rt < 4; ++rt)
          d2[rt] = __builtin_amdgcn_mfma_f32_16x16x32_bf16(af[rt], b2f[ks], d2[rt], 0, 0, 0);
      }

      if (MODE == 1) {
        #pragma unroll
        for (int rt = 0; rt < 4; ++rt)
          #pragma unroll
          for (int reg = 0; reg < 4; ++reg) {
            float y2 = d2[rt][reg] + b2v;
            s2a += y2; q2a += y2 * y2;
          }
      } else {  // MODE 2: per-gene head
        float pa[4][4];
        #pragma unroll
        for (int rt = 0; rt < 4; ++rt)
          #pragma unroll
          for (int reg = 0; reg < 4; ++reg) {
            int r = 16 * rt + l4 * 4 + reg;
            float o = fmaf(a2v, d2[rt][reg] + b2v, c2v);
            pa[rt][reg] = o * smiw[r * 68 + nn];
          }
        #pragma unroll
        for (int m = 1; m < 16; m <<= 1)
          #pragma unroll
          for (int rt = 0; rt < 4; ++rt)
            #pragma unroll
            for (int reg = 0; reg < 4; ++reg)
              pa[rt][reg] += __shfl_xor(pa[rt][reg], m);
        if (l15 == 0) {
          #pragma unroll
          for (int rt = 0; rt < 4; ++rt)
            #pragma unroll
            for (int reg = 0; reg < 4; ++reg)
              smwp[wid * 64 + 16 * rt + l4 * 4 + reg] = pa[rt][reg];
        }
        __syncthreads();   // (C)
        if (tid < 64) {
          int g = g0 + tid; if (tid >= rem) g -= GG;
          w_out[r0 + tid] = smwp[tid] + smwp[64 + tid] + smwp[128 + tid] + smwp[192 + tid] + ib1[g];
        }
      }
    }
  }

  // ---- flush stats ----
  if (MODE == 0) {
    #pragma unroll
    for (int jt = 0; jt < 2; ++jt) {
      float a = ss[jt], q = qq[jt];
      a += __shfl_xor(a, 16); a += __shfl_xor(a, 32);
      q += __shfl_xor(q, 16); q += __shfl_xor(q, 32);
      if (l4 == 0) {
        atomicAdd(&S1[wid * 32 + jt * 16 + l15], a);
        atomicAdd(&Q1[wid * 32 + jt * 16 + l15], q);
      }
    }
  }
  if (MODE == 1) {
    float a = s2a, q = q2a;
    a += __shfl_xor(a, 16); a += __shfl_xor(a, 32);
    q += __shfl_xor(q, 16); q += __shfl_xor(q, 32);
    if (l4 == 0) {
      atomicAdd(&S2[nn], a);
      atomicAdd(&Q2[nn], q);
    }
  }
}

// ---------- launcher ----------

extern "C" void kernel_launch(void* const* d_in, const int* in_sizes, int n_in,
                              void* d_out, int out_size, void* d_ws, size_t ws_size,
                              hipStream_t stream) {
  const float* expr     = (const float*)d_in[0];
  const int*   pert     = (const int*)d_in[1];
  const int*   ei       = (const int*)d_in[2];
  const float* ew       = (const float*)d_in[3];
  const float* gene_emb = (const float*)d_in[4];
  const float* pert_emb = (const float*)d_in[5];
  const float* bn_emb_g = (const float*)d_in[6];
  const float* bn_emb_b = (const float*)d_in[7];
  const float* sg_W     = (const float*)d_in[8];
  const float* sg_b     = (const float*)d_in[9];
  const float* pf_W1    = (const float*)d_in[10];
  const float* pf_b1    = (const float*)d_in[11];
  const float* pf_g1    = (const float*)d_in[12];
  const float* pf_be1   = (const float*)d_in[13];
  const float* pf_W2    = (const float*)d_in[14];
  const float* pf_b2    = (const float*)d_in[15];
  const float* pf_g2    = (const float*)d_in[16];
  const float* pf_be2   = (const float*)d_in[17];
  const float* bnp_g    = (const float*)d_in[18];
  const float* bnp_b    = (const float*)d_in[19];
  const float* r_W1     = (const float*)d_in[20];
  const float* r_b1     = (const float*)d_in[21];
  const float* r_g1     = (const float*)d_in[22];
  const float* r_be1    = (const float*)d_in[23];
  const float* r_W2     = (const float*)d_in[24];
  const float* r_b2     = (const float*)d_in[25];
  const float* r_g2     = (const float*)d_in[26];
  const float* r_be2    = (const float*)d_in[27];
  const float* iw1      = (const float*)d_in[28];
  const float* ib1      = (const float*)d_in[29];
  const float* c_W1     = (const float*)d_in[30];
  const float* c_b1     = (const float*)d_in[31];
  const float* c_g1     = (const float*)d_in[32];
  const float* c_be1    = (const float*)d_in[33];
  const float* c_W2     = (const float*)d_in[34];
  const float* c_b2     = (const float*)d_in[35];
  const float* c_g2     = (const float*)d_in[36];
  const float* c_be2    = (const float*)d_in[37];
  const float* iw2      = (const float*)d_in[38];
  const float* ib2      = (const float*)d_in[39];
  float* out = (float*)d_out;
  float* ws = (float*)d_ws;

  float* base = ws + 0;        // [G,H]
  float* rnp  = ws + 320000;   // [G,H]
  float* agg  = ws + 640000;   // [G,H]
  float* pge  = ws + 960000;   // [G,H]
  float* wv   = ws + 1280000;  // [B,G]
  float* dis  = ws + 1920000;  // [G]
  float* psum = ws + 1925120;  // [B,H]
  float* fusd = ws + 1933312;  // [B,H]
  float* tmpA = ws + 1941504;  // [B,H]
  float* crs  = ws + 1949696;  // [B,H]
  float* mtmp = ws + 1957888;
  float* vtmp = ws + 1958016;
  float* affa = ws + 1958144;
  float* affb = ws + 1958272;
  float* mb   = ws + 1958400;
  float* vb_  = ws + 1958464;
  float* mf   = ws + 1958528;
  float* vf   = ws + 1958592;
  float* az   = ws + 1958656;
  float* bz   = ws + 1958720;
  float* S1   = ws + 1958784;  // [128]
  float* Q1   = ws + 1958912;  // [128]
  float* S2   = ws + 1959040;  // [64]
  float* Q2   = ws + 1959104;  // [64]
  float* a1   = ws + 1959168;  // [128]
  float* b1c  = ws + 1959296;  // [128]
  float* a2   = ws + 1959424;  // [64]
  float* b2c  = ws + 1959488;  // [64]

  const int* src = ei;
  const int* dst = ei + EE;

  // --- gene embedding path
  renorm_rows<<<(GG + 3) / 4, 256, 0, stream>>>(gene_emb, base, GG);
  colstats<<<HH, 256, 0, stream>>>(base, GG, mtmp, vtmp);
  make_affine<<<1, 128, 0, stream>>>(bn_emb_g, bn_emb_b, mtmp, vtmp, affa, affb, HH);
  apply_affine<<<(GG * HH + 255) / 256, 256, 0, stream>>>(base, affa, affb, base, GG * HH, 1);
  colstats<<<HH, 256, 0, stream>>>(base, GG, mb, vb_);

  // --- SGConv path
  renorm_rows<<<(GG + 3) / 4, 256, 0, stream>>>(pert_emb, rnp, GG);
  hipMemsetAsync(dis, 0, GG * sizeof(float), stream);
  edge_deg<<<(EE + 255) / 256, 256, 0, stream>>>(dst, ew, dis);
  finish_dis<<<(GG + 255) / 256, 256, 0, stream>>>(dis);
  agg_init<<<(GG * HH + 255) / 256, 256, 0, stream>>>(dis, rnp, agg);
  agg_edges<<<(EE * 64 + 255) / 256, 256, 0, stream>>>(src, dst, ew, dis, rnp, agg);
  gemm_rows64<<<(GG + 3) / 4, 256, 0, stream>>>(agg, sg_W, sg_b, pge, GG, HH);
  psum_kernel<<<BB, 256, 0, stream>>>(pert, pge, psum);

  // --- pert_fuse MLP
  gemm_rows64<<<(BB + 3) / 4, 256, 0, stream>>>(psum, pf_W1, pf_b1, tmpA, BB, HH);
  colstats<<<HH, 256, 0, stream>>>(tmpA, BB, mtmp, vtmp);
  make_affine<<<1, 128, 0, stream>>>(pf_g1, pf_be1, mtmp, vtmp, affa, affb, HH);
  apply_affine<<<(BB * HH + 255) / 256, 256, 0, stream>>>(tmpA, affa, affb, tmpA, BB * HH, 1);
  gemm_rows64<<<(BB + 3) / 4, 256, 0, stream>>>(tmpA, pf_W2, pf_b2, fusd, BB, HH);
  colstats<<<HH, 256, 0, stream>>>(fusd, BB, mtmp, vtmp);
  make_affine<<<1, 128, 0, stream>>>(pf_g2, pf_be2, mtmp, vtmp, affa, affb, HH);
  apply_affine<<<(BB * HH + 255) / 256, 256, 0, stream>>>(fusd, affa, affb, fusd, BB * HH, 0);
  colstats<<<HH, 256, 0, stream>>>(fusd, BB, mf, vf);
  make_bnp<<<1, 64, 0, stream>>>(mb, vb_, mf, vf, bnp_g, bnp_b, az, bz);

  // --- recovery MLP over 640K rows (3 MFMA passes)
  hipMemsetAsync(S1, 0, 384 * sizeof(float), stream);
  big_kernel<0><<<768, 256, 0, stream>>>(base, fusd, az, bz, r_W1, r_b1, r_W2, r_b2,
                                         a1, b1c, a2, b2c, iw1, ib1, S1, Q1, S2, Q2, wv);
  finish_bn<<<1, 128, 0, stream>>>(S1, Q1, r_g1, r_be1, a1, b1c, 128, 1.0f / (float)RR);
  big_kernel<1><<<768, 256, 0, stream>>>(base, fusd, az, bz, r_W1, r_b1, r_W2, r_b2,
                                         a1, b1c, a2, b2c, iw1, ib1, S1, Q1, S2, Q2, wv);
  finish_bn<<<1, 128, 0, stream>>>(S2, Q2, r_g2, r_be2, a2, b2c, 64, 1.0f / (float)RR);
  big_kernel<2><<<768, 256, 0, stream>>>(base, fusd, az, bz, r_W1, r_b1, r_W2, r_b2,
                                         a1, b1c, a2, b2c, iw1, ib1, S1, Q1, S2, Q2, wv);

  // --- cross_gene_state MLP
  cross1_kernel<<<BB, 256, 0, stream>>>(wv, c_W1, c_b1, tmpA);
  colstats<<<HH, 256, 0, stream>>>(tmpA, BB, mtmp, vtmp);
  make_affine<<<1, 128, 0, stream>>>(c_g1, c_be1, mtmp, vtmp, affa, affb, HH);
  apply_affine<<<(BB * HH + 255) / 256, 256, 0, stream>>>(tmpA, affa, affb, tmpA, BB * HH, 1);
  gemm_rows64<<<(BB + 3) / 4, 256, 0, stream>>>(tmpA, c_W2, c_b2, crs, BB, HH);
  colstats<<<HH, 256, 0, stream>>>(crs, BB, mtmp, vtmp);
  make_affine<<<1, 128, 0, stream>>>(c_g2, c_be2, mtmp, vtmp, affa, affb, HH);
  apply_affine<<<(BB * HH + 255) / 256, 256, 0, stream>>>(crs, affa, affb, crs, BB * HH, 0);

  // --- final per-gene head + residual
  final_kernel<<<dim3((GG + 255) / 256, BB), 256, 0, stream>>>(wv, crs, iw2, ib2, expr, out);
}

// Round 4
// 754.367 us; speedup vs baseline: 2.8677x; 1.3314x over previous
//
#include <hip/hip_runtime.h>
#include <hip/hip_bf16.h>

#define GG 5000
#define BB 128
#define HH 64
#define EE 100000
#define RR (BB*GG)      // 640000 rows
#define NT (RR/64)      // 10000 tiles of 64 rows
#define EPS 1e-5f

typedef __attribute__((ext_vector_type(8))) short short8;
typedef __attribute__((ext_vector_type(4))) float f32x4;

__device__ __forceinline__ float dot4(const float4 a, const float4 b, float acc) {
  acc = fmaf(a.x, b.x, acc);
  acc = fmaf(a.y, b.y, acc);
  acc = fmaf(a.z, b.z, acc);
  acc = fmaf(a.w, b.w, acc);
  return acc;
}

__device__ __forceinline__ ushort f2b(float f) {
  union { float f; unsigned int u; } c; c.f = f;
  unsigned int u = c.u;
  return (ushort)((u + 0x7FFFu + ((u >> 16) & 1u)) >> 16);
}

// ---------- small kernels ----------

__global__ void renorm_rows(const float* __restrict__ X, float* __restrict__ out, int nrows) {
  int wid = threadIdx.x >> 6, lane = threadIdx.x & 63;
  int i = blockIdx.x * 4 + wid;
  if (i >= nrows) return;
  float v = X[i * HH + lane];
  float s = v * v;
  #pragma unroll
  for (int m = 1; m < 64; m <<= 1) s += __shfl_xor(s, m);
  float n = sqrtf(s);
  float scale = fminf(1.f, 1.f / fmaxf(n, 1e-12f));
  out[i * HH + lane] = v * scale;
}

__global__ void colstats(const float* __restrict__ X, int nrows,
                         float* __restrict__ mean, float* __restrict__ var) {
  int c = blockIdx.x;
  float s = 0.f, q = 0.f;
  for (int r = threadIdx.x; r < nrows; r += 256) {
    float v = X[r * HH + c];
    s += v; q += v * v;
  }
  __shared__ float ls[256], lq[256];
  ls[threadIdx.x] = s; lq[threadIdx.x] = q;
  __syncthreads();
  for (int o = 128; o > 0; o >>= 1) {
    if (threadIdx.x < o) { ls[threadIdx.x] += ls[threadIdx.x + o]; lq[threadIdx.x] += lq[threadIdx.x + o]; }
    __syncthreads();
  }
  if (threadIdx.x == 0) {
    float m = ls[0] / (float)nrows;
    mean[c] = m;
    var[c] = lq[0] / (float)nrows - m * m;
  }
}

__global__ void make_affine(const float* __restrict__ gamma, const float* __restrict__ beta,
                            const float* __restrict__ mean, const float* __restrict__ var,
                            float* __restrict__ a, float* __restrict__ b, int n) {
  int i = threadIdx.x;
  if (i < n) {
    float av = gamma[i] * rsqrtf(fmaxf(var[i], 0.f) + EPS);
    a[i] = av;
    b[i] = beta[i] - mean[i] * av;
  }
}

__global__ void apply_affine(const float* __restrict__ X, const float* __restrict__ a,
                             const float* __restrict__ b, float* __restrict__ out,
                             int total, int relu) {
  int i = blockIdx.x * 256 + threadIdx.x;
  if (i >= total) return;
  int c = i & 63;
  float v = fmaf(a[c], X[i], b[c]);
  out[i] = relu ? fmaxf(v, 0.f) : v;
}

__global__ void finish_bn(const float* __restrict__ S, const float* __restrict__ Q,
                          const float* __restrict__ gamma, const float* __restrict__ beta,
                          float* __restrict__ a, float* __restrict__ bc, int n, float inv_count) {
  int j = threadIdx.x;
  if (j < n) {
    float m = S[j] * inv_count;
    float v = Q[j] * inv_count - m * m;
    float av = gamma[j] * rsqrtf(fmaxf(v, 0.f) + EPS);
    a[j] = av;
    bc[j] = beta[j] - m * av;
  }
}

__global__ void make_bnp(const float* __restrict__ mb, const float* __restrict__ vb,
                         const float* __restrict__ mf, const float* __restrict__ vf,
                         const float* __restrict__ g, const float* __restrict__ bt,
                         float* __restrict__ az, float* __restrict__ bz) {
  int h = threadIdx.x;
  if (h < HH) {
    float a = g[h] * rsqrtf(vb[h] + vf[h] + EPS);
    az[h] = a;
    bz[h] = bt[h] - (mb[h] + mf[h]) * a;
  }
}

__global__ void edge_deg(const int* __restrict__ dst, const float* __restrict__ ew,
                         float* __restrict__ deg) {
  int e = blockIdx.x * 256 + threadIdx.x;
  if (e < EE) atomicAdd(&deg[dst[e]], ew[e]);
}
__global__ void finish_dis(float* __restrict__ deg) {
  int i = blockIdx.x * 256 + threadIdx.x;
  if (i < GG) deg[i] = rsqrtf(deg[i] + 1.0f);
}
__global__ void agg_init(const float* __restrict__ dis, const float* __restrict__ rnp,
                         float* __restrict__ agg) {
  int idx = blockIdx.x * 256 + threadIdx.x;
  if (idx < GG * HH) {
    int i = idx >> 6;
    float d = dis[i];
    agg[idx] = d * d * rnp[idx];
  }
}
__global__ void agg_edges(const int* __restrict__ src, const int* __restrict__ dst,
                          const float* __restrict__ ew, const float* __restrict__ dis,
                          const float* __restrict__ rnp, float* __restrict__ agg) {
  int idx = blockIdx.x * 256 + threadIdx.x;
  int e = idx >> 6, h = idx & 63;
  if (e < EE) {
    int s = src[e], d = dst[e];
    float c = dis[s] * ew[e] * dis[d];
    atomicAdd(&agg[d * HH + h], c * rnp[s * HH + h]);
  }
}

__global__ void gemm_rows64(const float* __restrict__ X, const float* __restrict__ W,
                            const float* __restrict__ bias, float* __restrict__ out,
                            int N, int M) {
  __shared__ float sx[4][HH];
  int wid = threadIdx.x >> 6, lane = threadIdx.x & 63;
  int i = blockIdx.x * 4 + wid;
  if (i < N) sx[wid][lane] = X[i * HH + lane];
  __syncthreads();
  if (i >= N) return;
  for (int j = lane; j < M; j += 64) {
    float acc = bias[j];
    const float* wr = W + j * HH;
    #pragma unroll 16
    for (int h = 0; h < HH; ++h) acc = fmaf(sx[wid][h], wr[h], acc);
    out[i * M + j] = acc;
  }
}

__global__ void psum_kernel(const int* __restrict__ pert, const float* __restrict__ pge,
                            float* __restrict__ out) {
  int b = blockIdx.x;
  int j = threadIdx.x & 63, part = threadIdx.x >> 6;
  float acc = 0.f;
  for (int g = part; g < GG; g += 4)
    acc = fmaf((float)pert[b * GG + g], pge[g * HH + j], acc);
  __shared__ float ls[256];
  ls[threadIdx.x] = acc;
  __syncthreads();
  if (part == 0) out[b * HH + j] = ls[j] + ls[j + 64] + ls[j + 128] + ls[j + 192];
}

// cross layer 1, wave-per-output: out[b,j] = bias[j] + sum_g wv[b,g]*Wc[j,g]
// lane index = g -> fully coalesced float4 loads on both operands.
__global__ void cross1_kernel(const float* __restrict__ wv, const float* __restrict__ Wc,
                              const float* __restrict__ bias, float* __restrict__ out) {
  int w = blockIdx.x * 4 + (threadIdx.x >> 6);   // 0..8191
  int lane = threadIdx.x & 63;
  int b = w >> 6, j = w & 63;
  const float* wr = wv + b * GG;
  const float* cr = Wc + j * GG;
  float acc = 0.f;
  #pragma unroll 4
  for (int i = 0; i < 19; ++i) {                 // 19*256 = 4864 g's
    int g = i * 256 + lane * 4;
    const float4 a = *(const float4*)(&wr[g]);
    const float4 c = *(const float4*)(&cr[g]);
    acc = dot4(a, c, acc);
  }
  for (int g = 4864 + lane; g < GG; g += 64)     // tail 136 g's
    acc = fmaf(wr[g], cr[g], acc);
  #pragma unroll
  for (int m = 1; m < 64; m <<= 1) acc += __shfl_xor(acc, m);
  if (lane == 0) out[b * HH + j] = bias[j] + acc;
}

// final head: block = (256 g's) x (16 b's); iw2 row loaded once per thread.
__global__ void final_kernel(const float* __restrict__ wv, const float* __restrict__ cross,
                             const float* __restrict__ iw2, const float* __restrict__ ib2,
                             const float* __restrict__ expr, float* __restrict__ out) {
  __shared__ float cs[16][HH];
  const int tid = threadIdx.x;
  const int b0 = blockIdx.y * 16;
  for (int i = tid; i < 16 * HH; i += 256)
    cs[i >> 6][i & 63] = cross[(b0 + (i >> 6)) * HH + (i & 63)];
  __syncthreads();
  int g = blockIdx.x * 256 + tid;
  if (g >= GG) return;
  float rw[65];
  const float* r = iw2 + g * 65;
  #pragma unroll
  for (int i = 0; i < 65; ++i) rw[i] = r[i];
  const float bg = ib2[g];
  for (int bi = 0; bi < 16; ++bi) {
    int b = b0 + bi;
    float acc = fmaf(wv[b * GG + g], rw[0], bg + expr[b * GG + g]);
    #pragma unroll 16
    for (int h = 0; h < HH; ++h) acc = fmaf(cs[bi][h], rw[1 + h], acc);
    out[b * GG + g] = acc;
  }
}

// ---------- MFMA big kernel over R=640K rows ----------
// MODE 0: y1 = z@W1^T + b1, accumulate column sum/sumsq -> S1,Q1
// MODE 1: recompute -> t=relu(a1*y1+b1c) -> y2 = t@W2^T + b2, accumulate S2,Q2
// MODE 2: full recompute -> out=a2*y2+b2c -> w[r] = sum_n out*iw1[g,n] + ib1[g]

template <int MODE>
__global__ __launch_bounds__(256, 3)
void big_kernel(const float* __restrict__ base, const float* __restrict__ fused,
                const float* __restrict__ az, const float* __restrict__ bz,
                const float* __restrict__ W1, const float* __restrict__ b1,
                const float* __restrict__ W2, const float* __restrict__ b2,
                const float* __restrict__ a1, const float* __restrict__ b1c,
                const float* __restrict__ a2, const float* __restrict__ b2c,
                const float* __restrict__ iw1, const float* __restrict__ ib1,
                float* __restrict__ S1, float* __restrict__ Q1,
                float* __restrict__ S2, float* __restrict__ Q2,
                float* __restrict__ w_out) {
  constexpr int SMEMB = (MODE == 0) ? 16384 : (MODE == 1) ? 32768 : 43008;
  __shared__ __align__(16) char sm[SMEMB];
  char* smz = sm;                      // [64][64] bf16, 8 KB  (steady)
  char* smt = sm + 8192;               // [64][128] bf16, 16 KB (MODE>0)
  float* smiw = (float*)(sm + 24576);  // [64][68] f32 (MODE2)
  float* smwp = (float*)(sm + 41984);  // [4][64] f32 (MODE2)
  // staging overlay (used once before main loop):
  char* smw1 = sm;                     // [128][64] bf16, 16 KB
  char* smw2 = sm + 16384;             // [64][128] bf16, 16 KB (MODE>0)

  const int tid = threadIdx.x;
  const int wid = tid >> 6;        // 0..3
  const int lane = tid & 63;
  const int l15 = lane & 15;
  const int l4 = lane >> 4;        // 0..3
  const int s = tid & 7;           // z-stage slot (stable across stage iters)

  // ---- stage W1 (and W2) as swizzled bf16 ----
  #pragma unroll
  for (int it = 0; it < 4; ++it) {
    int sid = tid + it * 256;          // 0..1023
    int j = sid >> 3, sl = sid & 7;
    const float4 lo = *(const float4*)(&W1[j * 64 + sl * 8]);
    const float4 hi = *(const float4*)(&W1[j * 64 + sl * 8 + 4]);
    union { short8 v; ushort u[8]; } pk;
    pk.u[0] = f2b(lo.x); pk.u[1] = f2b(lo.y); pk.u[2] = f2b(lo.z); pk.u[3] = f2b(lo.w);
    pk.u[4] = f2b(hi.x); pk.u[5] = f2b(hi.y); pk.u[6] = f2b(hi.z); pk.u[7] = f2b(hi.w);
    *(short8*)(smw1 + j * 128 + ((sl ^ (j & 7)) << 4)) = pk.v;
  }
  if (MODE > 0) {
    #pragma unroll
    for (int it = 0; it < 4; ++it) {
      int sid = tid + it * 256;        // 0..1023
      int n = sid >> 4, sl = sid & 15;
      const float4 lo = *(const float4*)(&W2[n * 128 + sl * 8]);
      const float4 hi = *(const float4*)(&W2[n * 128 + sl * 8 + 4]);
      union { short8 v; ushort u[8]; } pk;
      pk.u[0] = f2b(lo.x); pk.u[1] = f2b(lo.y); pk.u[2] = f2b(lo.z); pk.u[3] = f2b(lo.w);
      pk.u[4] = f2b(hi.x); pk.u[5] = f2b(hi.y); pk.u[6] = f2b(hi.z); pk.u[7] = f2b(hi.w);
      *(short8*)(smw2 + n * 256 + ((sl ^ (n & 15)) << 4)) = pk.v;
    }
  }
  __syncthreads();

  // ---- hoist W fragments into registers ----
  short8 b1f[2][2];   // [jt][ks]; col j = wid*32 + jt*16 + l15, k = l4*8 + 32*ks
  #pragma unroll
  for (int jt = 0; jt < 2; ++jt)
    #pragma unroll
    for (int ks = 0; ks < 2; ++ks) {
      int j = wid * 32 + jt * 16 + l15;
      b1f[jt][ks] = *(short8*)(smw1 + j * 128 + (((l4 + 4 * ks) ^ (l15 & 7)) << 4));
    }
  short8 b2f[4];      // [ks]; col n = wid*16 + l15, k = l4*8 + 32*ks
  if (MODE > 0) {
    #pragma unroll
    for (int ks = 0; ks < 4; ++ks) {
      int n = wid * 16 + l15;
      b2f[ks] = *(short8*)(smw2 + n * 256 + (((l4 + 4 * ks) ^ l15) << 4));
    }
  }
  __syncthreads();   // staging region now reusable as z/t

  // ---- per-thread constants ----
  const float4 azv0 = *(const float4*)(&az[s * 8]);
  const float4 azv1 = *(const float4*)(&az[s * 8 + 4]);
  const float4 bzv0 = *(const float4*)(&bz[s * 8]);
  const float4 bzv1 = *(const float4*)(&bz[s * 8 + 4]);
  float b1v[2], a1v[2], c1v[2];
  #pragma unroll
  for (int jt = 0; jt < 2; ++jt) {
    int j = wid * 32 + jt * 16 + l15;
    b1v[jt] = b1[j];
    if (MODE > 0) { a1v[jt] = a1[j]; c1v[jt] = b1c[j]; }
    else { a1v[jt] = 0.f; c1v[jt] = 0.f; }
  }
  const int nn = wid * 16 + l15;
  float b2v = 0, a2v = 0, c2v = 0;
  if (MODE > 0) b2v = b2[nn];
  if (MODE == 2) { a2v = a2[nn]; c2v = b2c[nn]; }

  float ss[2] = {0, 0}, qq[2] = {0, 0};   // MODE0
  float s2a = 0, q2a = 0;                 // MODE1

  for (int tile = blockIdx.x; tile < NT; tile += gridDim.x) {
    const int r0 = tile * 64;
    const int b0 = r0 / GG;
    const int g0 = r0 - b0 * GG;
    const int rem = GG - g0;   // rows before g wraps (tile wraps at most once)

    // ---- stage z tile (affine+relu+bf16, swizzled) ----
    #pragma unroll
    for (int it = 0; it < 2; ++it) {
      int sid = tid + it * 256;
      int rloc = sid >> 3;
      int g = g0 + rloc, bb = b0;
      if (rloc >= rem) { g -= GG; bb++; }
      const float4 x0 = *(const float4*)(&base[g * 64 + s * 8]);
      const float4 x1 = *(const float4*)(&base[g * 64 + s * 8 + 4]);
      const float4 f0 = *(const float4*)(&fused[bb * 64 + s * 8]);
      const float4 f1 = *(const float4*)(&fused[bb * 64 + s * 8 + 4]);
      union { short8 v; ushort u[8]; } pk;
      pk.u[0] = f2b(fmaxf(fmaf(azv0.x, x0.x + f0.x, bzv0.x), 0.f));
      pk.u[1] = f2b(fmaxf(fmaf(azv0.y, x0.y + f0.y, bzv0.y), 0.f));
      pk.u[2] = f2b(fmaxf(fmaf(azv0.z, x0.z + f0.z, bzv0.z), 0.f));
      pk.u[3] = f2b(fmaxf(fmaf(azv0.w, x0.w + f0.w, bzv0.w), 0.f));
      pk.u[4] = f2b(fmaxf(fmaf(azv1.x, x1.x + f1.x, bzv1.x), 0.f));
      pk.u[5] = f2b(fmaxf(fmaf(azv1.y, x1.y + f1.y, bzv1.y), 0.f));
      pk.u[6] = f2b(fmaxf(fmaf(azv1.z, x1.z + f1.z, bzv1.z), 0.f));
      pk.u[7] = f2b(fmaxf(fmaf(azv1.w, x1.w + f1.w, bzv1.w), 0.f));
      *(short8*)(smz + rloc * 128 + ((s ^ (rloc & 7)) << 4)) = pk.v;
    }
    if (MODE == 2) {
      int rloc = tid >> 2, c0 = (tid & 3) * 16;
      int g = g0 + rloc; if (rloc >= rem) g -= GG;
      #pragma unroll
      for (int i = 0; i < 4; ++i)
        *(float4*)(&smiw[rloc * 68 + c0 + 4 * i]) = *(const float4*)(&iw1[g * 64 + c0 + 4 * i]);
    }
    __syncthreads();   // (A)

    // ---- GEMM1: D1[rt][jt] ----
    f32x4 d1[4][2];
    #pragma unroll
    for (int rt = 0; rt < 4; ++rt)
      #pragma unroll
      for (int jt = 0; jt < 2; ++jt) d1[rt][jt] = (f32x4){0.f, 0.f, 0.f, 0.f};
    #pragma unroll
    for (int ks = 0; ks < 2; ++ks) {
      short8 af[4];
      #pragma unroll
      for (int rt = 0; rt < 4; ++rt) {
        int r = 16 * rt + l15;
        af[rt] = *(short8*)(smz + r * 128 + (((l4 + 4 * ks) ^ (l15 & 7)) << 4));
      }
      #pragma unroll
      for (int jt = 0; jt < 2; ++jt)
        #pragma unroll
        for (int rt = 0; rt < 4; ++rt)
          d1[rt][jt] = __builtin_amdgcn_mfma_f32_16x16x32_bf16(af[rt], b1f[jt][ks], d1[rt][jt], 0, 0, 0);
    }

    if (MODE == 0) {
      #pragma unroll
      for (int rt = 0; rt < 4; ++rt)
        #pragma unroll
        for (int jt = 0; jt < 2; ++jt)
          #pragma unroll
          for (int reg = 0; reg < 4; ++reg) {
            float y = d1[rt][jt][reg] + b1v[jt];
            ss[jt] += y; qq[jt] += y * y;
          }
      __syncthreads();   // guard next z-stage vs this GEMM1's reads
    } else {
      // ---- epilogue1: t = relu(a1*y1+b1c) -> LDS bf16 (swizzled) ----
      #pragma unroll
      for (int rt = 0; rt < 4; ++rt)
        #pragma unroll
        for (int jt = 0; jt < 2; ++jt) {
          int j = wid * 32 + jt * 16 + l15;
          int jhi = j >> 3, jlo = j & 7;
          #pragma unroll
          for (int reg = 0; reg < 4; ++reg) {
            int r = 16 * rt + l4 * 4 + reg;
            float y = d1[rt][jt][reg] + b1v[jt];
            float tv = fmaxf(fmaf(a1v[jt], y, c1v[jt]), 0.f);
            *(ushort*)(smt + r * 256 + ((jhi ^ (r & 15)) << 4) + jlo * 2) = f2b(tv);
          }
        }
      __syncthreads();   // (B)

      // ---- GEMM2: D2[rt], cols n = wid*16+l15 ----
      f32x4 d2[4];
      #pragma unroll
      for (int rt = 0; rt < 4; ++rt) d2[rt] = (f32x4){0.f, 0.f, 0.f, 0.f};
      #pragma unroll
      for (int ks = 0; ks < 4; ++ks) {
        short8 af[4];
        #pragma unroll
        for (int rt = 0; rt < 4; ++rt) {
          int r = 16 * rt + l15;
          af[rt] = *(short8*)(smt + r * 256 + (((l4 + 4 * ks) ^ l15) << 4));
        }
        #pragma unroll
        for (int rt = 0; rt < 4; ++rt)
          d2[rt] = __builtin_amdgcn_mfma_f32_16x16x32_bf16(af[rt], b2f[ks], d2[rt], 0, 0, 0);
      }

      if (MODE == 1) {
        #pragma unroll
        for (int rt = 0; rt < 4; ++rt)
          #pragma unroll
          for (int reg = 0; reg < 4; ++reg) {
            float y2 = d2[rt][reg] + b2v;
            s2a += y2; q2a += y2 * y2;
          }
      } else {  // MODE 2: per-gene head
        float pa[4][4];
        #pragma unroll
        for (int rt = 0; rt < 4; ++rt)
          #pragma unroll
          for (int reg = 0; reg < 4; ++reg) {
            int r = 16 * rt + l4 * 4 + reg;
            float o = fmaf(a2v, d2[rt][reg] + b2v, c2v);
            pa[rt][reg] = o * smiw[r * 68 + nn];
          }
        #pragma unroll
        for (int m = 1; m < 16; m <<= 1)
          #pragma unroll
          for (int rt = 0; rt < 4; ++rt)
            #pragma unroll
            for (int reg = 0; reg < 4; ++reg)
              pa[rt][reg] += __shfl_xor(pa[rt][reg], m);
        if (l15 == 0) {
          #pragma unroll
          for (int rt = 0; rt < 4; ++rt)
            #pragma unroll
            for (int reg = 0; reg < 4; ++reg)
              smwp[wid * 64 + 16 * rt + l4 * 4 + reg] = pa[rt][reg];
        }
        __syncthreads();   // (C)
        if (tid < 64) {
          int g = g0 + tid; if (tid >= rem) g -= GG;
          w_out[r0 + tid] = smwp[tid] + smwp[64 + tid] + smwp[128 + tid] + smwp[192 + tid] + ib1[g];
        }
      }
    }
  }

  // ---- flush stats ----
  if (MODE == 0) {
    #pragma unroll
    for (int jt = 0; jt < 2; ++jt) {
      float a = ss[jt], q = qq[jt];
      a += __shfl_xor(a, 16); a += __shfl_xor(a, 32);
      q += __shfl_xor(q, 16); q += __shfl_xor(q, 32);
      if (l4 == 0) {
        atomicAdd(&S1[wid * 32 + jt * 16 + l15], a);
        atomicAdd(&Q1[wid * 32 + jt * 16 + l15], q);
      }
    }
  }
  if (MODE == 1) {
    float a = s2a, q = q2a;
    a += __shfl_xor(a, 16); a += __shfl_xor(a, 32);
    q += __shfl_xor(q, 16); q += __shfl_xor(q, 32);
    if (l4 == 0) {
      atomicAdd(&S2[nn], a);
      atomicAdd(&Q2[nn], q);
    }
  }
}

// ---------- launcher ----------

extern "C" void kernel_launch(void* const* d_in, const int* in_sizes, int n_in,
                              void* d_out, int out_size, void* d_ws, size_t ws_size,
                              hipStream_t stream) {
  const float* expr     = (const float*)d_in[0];
  const int*   pert     = (const int*)d_in[1];
  const int*   ei       = (const int*)d_in[2];
  const float* ew       = (const float*)d_in[3];
  const float* gene_emb = (const float*)d_in[4];
  const float* pert_emb = (const float*)d_in[5];
  const float* bn_emb_g = (const float*)d_in[6];
  const float* bn_emb_b = (const float*)d_in[7];
  const float* sg_W     = (const float*)d_in[8];
  const float* sg_b     = (const float*)d_in[9];
  const float* pf_W1    = (const float*)d_in[10];
  const float* pf_b1    = (const float*)d_in[11];
  const float* pf_g1    = (const float*)d_in[12];
  const float* pf_be1   = (const float*)d_in[13];
  const float* pf_W2    = (const float*)d_in[14];
  const float* pf_b2    = (const float*)d_in[15];
  const float* pf_g2    = (const float*)d_in[16];
  const float* pf_be2   = (const float*)d_in[17];
  const float* bnp_g    = (const float*)d_in[18];
  const float* bnp_b    = (const float*)d_in[19];
  const float* r_W1     = (const float*)d_in[20];
  const float* r_b1     = (const float*)d_in[21];
  const float* r_g1     = (const float*)d_in[22];
  const float* r_be1    = (const float*)d_in[23];
  const float* r_W2     = (const float*)d_in[24];
  const float* r_b2     = (const float*)d_in[25];
  const float* r_g2     = (const float*)d_in[26];
  const float* r_be2    = (const float*)d_in[27];
  const float* iw1      = (const float*)d_in[28];
  const float* ib1      = (const float*)d_in[29];
  const float* c_W1     = (const float*)d_in[30];
  const float* c_b1     = (const float*)d_in[31];
  const float* c_g1     = (const float*)d_in[32];
  const float* c_be1    = (const float*)d_in[33];
  const float* c_W2     = (const float*)d_in[34];
  const float* c_b2     = (const float*)d_in[35];
  const float* c_g2     = (const float*)d_in[36];
  const float* c_be2    = (const float*)d_in[37];
  const float* iw2      = (const float*)d_in[38];
  const float* ib2      = (const float*)d_in[39];
  float* out = (float*)d_out;
  float* ws = (float*)d_ws;

  float* base = ws + 0;        // [G,H]
  float* rnp  = ws + 320000;   // [G,H]
  float* agg  = ws + 640000;   // [G,H]
  float* pge  = ws + 960000;   // [G,H]
  float* wv   = ws + 1280000;  // [B,G]
  float* dis  = ws + 1920000;  // [G]
  float* psum = ws + 1925120;  // [B,H]
  float* fusd = ws + 1933312;  // [B,H]
  float* tmpA = ws + 1941504;  // [B,H]
  float* crs  = ws + 1949696;  // [B,H]
  float* mtmp = ws + 1957888;
  float* vtmp = ws + 1958016;
  float* affa = ws + 1958144;
  float* affb = ws + 1958272;
  float* mb   = ws + 1958400;
  float* vb_  = ws + 1958464;
  float* mf   = ws + 1958528;
  float* vf   = ws + 1958592;
  float* az   = ws + 1958656;
  float* bz   = ws + 1958720;
  float* S1   = ws + 1958784;  // [128]
  float* Q1   = ws + 1958912;  // [128]
  float* S2   = ws + 1959040;  // [64]
  float* Q2   = ws + 1959104;  // [64]
  float* a1   = ws + 1959168;  // [128]
  float* b1c  = ws + 1959296;  // [128]
  float* a2   = ws + 1959424;  // [64]
  float* b2c  = ws + 1959488;  // [64]

  const int* src = ei;
  const int* dst = ei + EE;

  // --- gene embedding path
  renorm_rows<<<(GG + 3) / 4, 256, 0, stream>>>(gene_emb, base, GG);
  colstats<<<HH, 256, 0, stream>>>(base, GG, mtmp, vtmp);
  make_affine<<<1, 128, 0, stream>>>(bn_emb_g, bn_emb_b, mtmp, vtmp, affa, affb, HH);
  apply_affine<<<(GG * HH + 255) / 256, 256, 0, stream>>>(base, affa, affb, base, GG * HH, 1);
  colstats<<<HH, 256, 0, stream>>>(base, GG, mb, vb_);

  // --- SGConv path
  renorm_rows<<<(GG + 3) / 4, 256, 0, stream>>>(pert_emb, rnp, GG);
  hipMemsetAsync(dis, 0, GG * sizeof(float), stream);
  edge_deg<<<(EE + 255) / 256, 256, 0, stream>>>(dst, ew, dis);
  finish_dis<<<(GG + 255) / 256, 256, 0, stream>>>(dis);
  agg_init<<<(GG * HH + 255) / 256, 256, 0, stream>>>(dis, rnp, agg);
  agg_edges<<<(EE * 64 + 255) / 256, 256, 0, stream>>>(src, dst, ew, dis, rnp, agg);
  gemm_rows64<<<(GG + 3) / 4, 256, 0, stream>>>(agg, sg_W, sg_b, pge, GG, HH);
  psum_kernel<<<BB, 256, 0, stream>>>(pert, pge, psum);

  // --- pert_fuse MLP
  gemm_rows64<<<(BB + 3) / 4, 256, 0, stream>>>(psum, pf_W1, pf_b1, tmpA, BB, HH);
  colstats<<<HH, 256, 0, stream>>>(tmpA, BB, mtmp, vtmp);
  make_affine<<<1, 128, 0, stream>>>(pf_g1, pf_be1, mtmp, vtmp, affa, affb, HH);
  apply_affine<<<(BB * HH + 255) / 256, 256, 0, stream>>>(tmpA, affa, affb, tmpA, BB * HH, 1);
  gemm_rows64<<<(BB + 3) / 4, 256, 0, stream>>>(tmpA, pf_W2, pf_b2, fusd, BB, HH);
  colstats<<<HH, 256, 0, stream>>>(fusd, BB, mtmp, vtmp);
  make_affine<<<1, 128, 0, stream>>>(pf_g2, pf_be2, mtmp, vtmp, affa, affb, HH);
  apply_affine<<<(BB * HH + 255) / 256, 256, 0, stream>>>(fusd, affa, affb, fusd, BB * HH, 0);
  colstats<<<HH, 256, 0, stream>>>(fusd, BB, mf, vf);
  make_bnp<<<1, 64, 0, stream>>>(mb, vb_, mf, vf, bnp_g, bnp_b, az, bz);

  // --- recovery MLP over 640K rows (3 MFMA passes)
  hipMemsetAsync(S1, 0, 384 * sizeof(float), stream);
  big_kernel<0><<<768, 256, 0, stream>>>(base, fusd, az, bz, r_W1, r_b1, r_W2, r_b2,
                                         a1, b1c, a2, b2c, iw1, ib1, S1, Q1, S2, Q2, wv);
  finish_bn<<<1, 128, 0, stream>>>(S1, Q1, r_g1, r_be1, a1, b1c, 128, 1.0f / (float)RR);
  big_kernel<1><<<768, 256, 0, stream>>>(base, fusd, az, bz, r_W1, r_b1, r_W2, r_b2,
                                         a1, b1c, a2, b2c, iw1, ib1, S1, Q1, S2, Q2, wv);
  finish_bn<<<1, 128, 0, stream>>>(S2, Q2, r_g2, r_be2, a2, b2c, 64, 1.0f / (float)RR);
  big_kernel<2><<<768, 256, 0, stream>>>(base, fusd, az, bz, r_W1, r_b1, r_W2, r_b2,
                                         a1, b1c, a2, b2c, iw1, ib1, S1, Q1, S2, Q2, wv);

  // --- cross_gene_state MLP
  cross1_kernel<<<2048, 256, 0, stream>>>(wv, c_W1, c_b1, tmpA);
  colstats<<<HH, 256, 0, stream>>>(tmpA, BB, mtmp, vtmp);
  make_affine<<<1, 128, 0, stream>>>(c_g1, c_be1, mtmp, vtmp, affa, affb, HH);
  apply_affine<<<(BB * HH + 255) / 256, 256, 0, stream>>>(tmpA, affa, affb, tmpA, BB * HH, 1);
  gemm_rows64<<<(BB + 3) / 4, 256, 0, stream>>>(tmpA, c_W2, c_b2, crs, BB, HH);
  colstats<<<HH, 256, 0, stream>>>(crs, BB, mtmp, vtmp);
  make_affine<<<1, 128, 0, stream>>>(c_g2, c_be2, mtmp, vtmp, affa, affb, HH);
  apply_affine<<<(BB * HH + 255) / 256, 256, 0, stream>>>(crs, affa, affb, crs, BB * HH, 0);

  // --- final per-gene head + residual
  final_kernel<<<dim3((GG + 255) / 256, BB / 16), 256, 0, stream>>>(wv, crs, iw2, ib2, expr, out);
}

// Round 5
// 460.160 us; speedup vs baseline: 4.7012x; 1.6394x over previous
//
#include <hip/hip_runtime.h>
#include <hip/hip_bf16.h>

#define GG 5000
#define BB 128
#define HH 64
#define EE 100000
#define RR (BB*GG)      // 640000 rows
#define NT (RR/64)      // 10000 tiles of 64 rows
#define EPS 1e-5f

typedef __attribute__((ext_vector_type(8))) short short8;
typedef __attribute__((ext_vector_type(4))) float f32x4;

__device__ __forceinline__ float dot4(const float4 a, const float4 b, float acc) {
  acc = fmaf(a.x, b.x, acc);
  acc = fmaf(a.y, b.y, acc);
  acc = fmaf(a.z, b.z, acc);
  acc = fmaf(a.w, b.w, acc);
  return acc;
}

__device__ __forceinline__ ushort f2b(float f) {
  union { float f; unsigned int u; } c; c.f = f;
  unsigned int u = c.u;
  return (ushort)((u + 0x7FFFu + ((u >> 16) & 1u)) >> 16);
}

// ---------- small kernels ----------

__global__ void renorm_rows(const float* __restrict__ X, float* __restrict__ out, int nrows) {
  int wid = threadIdx.x >> 6, lane = threadIdx.x & 63;
  int i = blockIdx.x * 4 + wid;
  if (i >= nrows) return;
  float v = X[i * HH + lane];
  float s = v * v;
  #pragma unroll
  for (int m = 1; m < 64; m <<= 1) s += __shfl_xor(s, m);
  float n = sqrtf(s);
  float scale = fminf(1.f, 1.f / fmaxf(n, 1e-12f));
  out[i * HH + lane] = v * scale;
}

// coalesced column sums: lane = col, waves stride rows; atomicAdd into S/Q (pre-zeroed)
__global__ void colsum(const float* __restrict__ X, int nrows,
                       float* __restrict__ S, float* __restrict__ Q) {
  int lane = threadIdx.x & 63, w = threadIdx.x >> 6;
  float s = 0.f, q = 0.f;
  for (int r = blockIdx.x * 4 + w; r < nrows; r += gridDim.x * 4) {
    float v = X[r * HH + lane];
    s += v; q += v * v;
  }
  __shared__ float ls[256], lq[256];
  ls[threadIdx.x] = s; lq[threadIdx.x] = q;
  __syncthreads();
  if (w == 0) {
    s = ls[lane] + ls[lane + 64] + ls[lane + 128] + ls[lane + 192];
    q = lq[lane] + lq[lane + 64] + lq[lane + 128] + lq[lane + 192];
    atomicAdd(&S[lane], s);
    atomicAdd(&Q[lane], q);
  }
}

// BN affine from accumulated sums: a = gamma*rsqrt(Q/n-(S/n)^2+eps); b = beta - mean*a
__global__ void finish_bn(const float* __restrict__ S, const float* __restrict__ Q,
                          const float* __restrict__ gamma, const float* __restrict__ beta,
                          float* __restrict__ a, float* __restrict__ bc, int n, float inv_count) {
  int j = threadIdx.x;
  if (j < n) {
    float m = S[j] * inv_count;
    float v = Q[j] * inv_count - m * m;
    float av = gamma[j] * rsqrtf(fmaxf(v, 0.f) + EPS);
    a[j] = av;
    bc[j] = beta[j] - m * av;
  }
}

__global__ void apply_affine(const float* __restrict__ X, const float* __restrict__ a,
                             const float* __restrict__ b, float* __restrict__ out,
                             int total, int relu) {
  int i = blockIdx.x * 256 + threadIdx.x;
  if (i >= total) return;
  int c = i & 63;
  float v = fmaf(a[c], X[i], b[c]);
  out[i] = relu ? fmaxf(v, 0.f) : v;
}

// bnp stats decomposition from raw sums: z = base[g,h]+fused[b,h]
__global__ void make_bnp(const float* __restrict__ Sb, const float* __restrict__ Qb,
                         const float* __restrict__ Sf, const float* __restrict__ Qf,
                         const float* __restrict__ g, const float* __restrict__ bt,
                         float* __restrict__ az, float* __restrict__ bz) {
  int h = threadIdx.x;
  if (h < HH) {
    float mb = Sb[h] * (1.f / GG), vb = Qb[h] * (1.f / GG) - mb * mb;
    float mf = Sf[h] * (1.f / BB), vf = Qf[h] * (1.f / BB) - mf * mf;
    float a = g[h] * rsqrtf(fmaxf(vb, 0.f) + fmaxf(vf, 0.f) + EPS);
    az[h] = a;
    bz[h] = bt[h] - (mb + mf) * a;
  }
}

__global__ void edge_deg(const int* __restrict__ dst, const float* __restrict__ ew,
                         float* __restrict__ deg) {
  int e = blockIdx.x * 256 + threadIdx.x;
  if (e < EE) atomicAdd(&deg[dst[e]], ew[e]);
}
__global__ void finish_dis(float* __restrict__ deg) {
  int i = blockIdx.x * 256 + threadIdx.x;
  if (i < GG) deg[i] = rsqrtf(deg[i] + 1.0f);
}
__global__ void agg_init(const float* __restrict__ dis, const float* __restrict__ rnp,
                         float* __restrict__ agg) {
  int idx = blockIdx.x * 256 + threadIdx.x;
  if (idx < GG * HH) {
    int i = idx >> 6;
    float d = dis[i];
    agg[idx] = d * d * rnp[idx];
  }
}
__global__ void agg_edges(const int* __restrict__ src, const int* __restrict__ dst,
                          const float* __restrict__ ew, const float* __restrict__ dis,
                          const float* __restrict__ rnp, float* __restrict__ agg) {
  int idx = blockIdx.x * 256 + threadIdx.x;
  int e = idx >> 6, h = idx & 63;
  if (e < EE) {
    int s = src[e], d = dst[e];
    float c = dis[s] * ew[e] * dis[d];
    atomicAdd(&agg[d * HH + h], c * rnp[s * HH + h]);
  }
}

__global__ void gemm_rows64(const float* __restrict__ X, const float* __restrict__ W,
                            const float* __restrict__ bias, float* __restrict__ out,
                            int N, int M) {
  __shared__ float sx[4][HH];
  int wid = threadIdx.x >> 6, lane = threadIdx.x & 63;
  int i = blockIdx.x * 4 + wid;
  if (i < N) sx[wid][lane] = X[i * HH + lane];
  __syncthreads();
  if (i >= N) return;
  for (int j = lane; j < M; j += 64) {
    float acc = bias[j];
    const float* wr = W + j * HH;
    #pragma unroll 16
    for (int h = 0; h < HH; ++h) acc = fmaf(sx[wid][h], wr[h], acc);
    out[i * M + j] = acc;
  }
}

// psum[b,j] += sum over this block's g-chunk of pert[b,g]*pge[g,j]
// grid = (BB, 10); chunk of 500 g; 4 independent accumulator chains per wave.
__global__ void psum_kernel(const int* __restrict__ pert, const float* __restrict__ pge,
                            float* __restrict__ out) {
  int b = blockIdx.x;
  int g0 = blockIdx.y * 500;
  int j = threadIdx.x & 63, part = threadIdx.x >> 6;
  const int* pr = pert + b * GG;
  float a0 = 0.f, a1 = 0.f, a2 = 0.f, a3 = 0.f;
  #pragma unroll 2
  for (int i = 0; i < 124; i += 4) {
    int g = g0 + part + 4 * i;
    a0 = fmaf((float)pr[g],      pge[(g)      * HH + j], a0);
    a1 = fmaf((float)pr[g + 4],  pge[(g + 4)  * HH + j], a1);
    a2 = fmaf((float)pr[g + 8],  pge[(g + 8)  * HH + j], a2);
    a3 = fmaf((float)pr[g + 12], pge[(g + 12) * HH + j], a3);
  }
  { int g = g0 + part + 496; a0 = fmaf((float)pr[g], pge[g * HH + j], a0); }
  float acc = (a0 + a1) + (a2 + a3);
  __shared__ float ls[256];
  ls[threadIdx.x] = acc;
  __syncthreads();
  if (part == 0) atomicAdd(&out[b * HH + j], ls[j] + ls[j + 64] + ls[j + 128] + ls[j + 192]);
}

// cross layer 1, wave-per-output: out[b,j] = bias[j] + sum_g wv[b,g]*Wc[j,g]
__global__ void cross1_kernel(const float* __restrict__ wv, const float* __restrict__ Wc,
                              const float* __restrict__ bias, float* __restrict__ out) {
  int w = blockIdx.x * 4 + (threadIdx.x >> 6);   // 0..8191
  int lane = threadIdx.x & 63;
  int b = w >> 6, j = w & 63;
  const float* wr = wv + b * GG;
  const float* cr = Wc + j * GG;
  float acc = 0.f;
  #pragma unroll 4
  for (int i = 0; i < 19; ++i) {                 // 19*256 = 4864 g's
    int g = i * 256 + lane * 4;
    const float4 a = *(const float4*)(&wr[g]);
    const float4 c = *(const float4*)(&cr[g]);
    acc = dot4(a, c, acc);
  }
  for (int g = 4864 + lane; g < GG; g += 64)     // tail 136 g's
    acc = fmaf(wr[g], cr[g], acc);
  #pragma unroll
  for (int m = 1; m < 64; m <<= 1) acc += __shfl_xor(acc, m);
  if (lane == 0) out[b * HH + j] = bias[j] + acc;
}

// final head: block = (256 g's) x (16 b's); iw2 row in registers (fully static indexing).
__global__ void final_kernel(const float* __restrict__ wv, const float* __restrict__ cross,
                             const float* __restrict__ iw2, const float* __restrict__ ib2,
                             const float* __restrict__ expr, float* __restrict__ out) {
  __shared__ float cs[16][HH];
  const int tid = threadIdx.x;
  const int b0 = blockIdx.y * 16;
  for (int i = tid; i < 16 * HH; i += 256)
    cs[i >> 6][i & 63] = cross[(b0 + (i >> 6)) * HH + (i & 63)];
  __syncthreads();
  int g = blockIdx.x * 256 + tid;
  if (g >= GG) return;
  float rw[65];
  const float* r = iw2 + g * 65;
  #pragma unroll
  for (int i = 0; i < 65; ++i) rw[i] = r[i];
  const float bg = ib2[g];
  for (int bi = 0; bi < 16; ++bi) {
    int b = b0 + bi;
    float acc = fmaf(wv[b * GG + g], rw[0], bg + expr[b * GG + g]);
    #pragma unroll
    for (int h = 0; h < HH; ++h) acc = fmaf(cs[bi][h], rw[1 + h], acc);
    out[b * GG + g] = acc;
  }
}

// ---------- MFMA big kernel over R=640K rows ----------
// MODE 0: y1 = z@W1^T + b1, accumulate column sum/sumsq -> S1,Q1
// MODE 1: recompute -> t=relu(a1*y1+b1c) -> y2 = t@W2^T + b2, accumulate S2,Q2
// MODE 2: full recompute -> out=a2*y2+b2c -> w[r] = sum_n out*iw1[g,n] + ib1[g]

template <int MODE>
__global__ __launch_bounds__(256, 3)
void big_kernel(const float* __restrict__ base, const float* __restrict__ fused,
                const float* __restrict__ az, const float* __restrict__ bz,
                const float* __restrict__ W1, const float* __restrict__ b1,
                const float* __restrict__ W2, const float* __restrict__ b2,
                const float* __restrict__ a1, const float* __restrict__ b1c,
                const float* __restrict__ a2, const float* __restrict__ b2c,
                const float* __restrict__ iw1, const float* __restrict__ ib1,
                float* __restrict__ S1, float* __restrict__ Q1,
                float* __restrict__ S2, float* __restrict__ Q2,
                float* __restrict__ w_out) {
  constexpr int SMEMB = (MODE == 0) ? 16384 : (MODE == 1) ? 32768 : 43008;
  __shared__ __align__(16) char sm[SMEMB];
  char* smz = sm;                      // [64][64] bf16, 8 KB  (steady)
  char* smt = sm + 8192;               // [64][128] bf16, 16 KB (MODE>0)
  float* smiw = (float*)(sm + 24576);  // [64][68] f32 (MODE2)
  float* smwp = (float*)(sm + 41984);  // [4][64] f32 (MODE2)
  // staging overlay (used once before main loop):
  char* smw1 = sm;                     // [128][64] bf16, 16 KB
  char* smw2 = sm + 16384;             // [64][128] bf16, 16 KB (MODE>0)

  const int tid = threadIdx.x;
  const int wid = tid >> 6;        // 0..3
  const int lane = tid & 63;
  const int l15 = lane & 15;
  const int l4 = lane >> 4;        // 0..3
  const int s = tid & 7;           // z-stage slot (stable across stage iters)

  // ---- stage W1 (and W2) as swizzled bf16 ----
  #pragma unroll
  for (int it = 0; it < 4; ++it) {
    int sid = tid + it * 256;          // 0..1023
    int j = sid >> 3, sl = sid & 7;
    const float4 lo = *(const float4*)(&W1[j * 64 + sl * 8]);
    const float4 hi = *(const float4*)(&W1[j * 64 + sl * 8 + 4]);
    union { short8 v; ushort u[8]; } pk;
    pk.u[0] = f2b(lo.x); pk.u[1] = f2b(lo.y); pk.u[2] = f2b(lo.z); pk.u[3] = f2b(lo.w);
    pk.u[4] = f2b(hi.x); pk.u[5] = f2b(hi.y); pk.u[6] = f2b(hi.z); pk.u[7] = f2b(hi.w);
    *(short8*)(smw1 + j * 128 + ((sl ^ (j & 7)) << 4)) = pk.v;
  }
  if (MODE > 0) {
    #pragma unroll
    for (int it = 0; it < 4; ++it) {
      int sid = tid + it * 256;        // 0..1023
      int n = sid >> 4, sl = sid & 15;
      const float4 lo = *(const float4*)(&W2[n * 128 + sl * 8]);
      const float4 hi = *(const float4*)(&W2[n * 128 + sl * 8 + 4]);
      union { short8 v; ushort u[8]; } pk;
      pk.u[0] = f2b(lo.x); pk.u[1] = f2b(lo.y); pk.u[2] = f2b(lo.z); pk.u[3] = f2b(lo.w);
      pk.u[4] = f2b(hi.x); pk.u[5] = f2b(hi.y); pk.u[6] = f2b(hi.z); pk.u[7] = f2b(hi.w);
      *(short8*)(smw2 + n * 256 + ((sl ^ (n & 15)) << 4)) = pk.v;
    }
  }
  __syncthreads();

  // ---- hoist W fragments into registers ----
  short8 b1f[2][2];   // [jt][ks]; col j = wid*32 + jt*16 + l15, k = l4*8 + 32*ks
  #pragma unroll
  for (int jt = 0; jt < 2; ++jt)
    #pragma unroll
    for (int ks = 0; ks < 2; ++ks) {
      int j = wid * 32 + jt * 16 + l15;
      b1f[jt][ks] = *(short8*)(smw1 + j * 128 + (((l4 + 4 * ks) ^ (l15 & 7)) << 4));
    }
  short8 b2f[4];      // [ks]; col n = wid*16 + l15, k = l4*8 + 32*ks
  if (MODE > 0) {
    #pragma unroll
    for (int ks = 0; ks < 4; ++ks) {
      int n = wid * 16 + l15;
      b2f[ks] = *(short8*)(smw2 + n * 256 + (((l4 + 4 * ks) ^ l15) << 4));
    }
  }
  __syncthreads();   // staging region now reusable as z/t

  // ---- per-thread constants ----
  const float4 azv0 = *(const float4*)(&az[s * 8]);
  const float4 azv1 = *(const float4*)(&az[s * 8 + 4]);
  const float4 bzv0 = *(const float4*)(&bz[s * 8]);
  const float4 bzv1 = *(const float4*)(&bz[s * 8 + 4]);
  float b1v[2], a1v[2], c1v[2];
  #pragma unroll
  for (int jt = 0; jt < 2; ++jt) {
    int j = wid * 32 + jt * 16 + l15;
    b1v[jt] = b1[j];
    if (MODE > 0) { a1v[jt] = a1[j]; c1v[jt] = b1c[j]; }
    else { a1v[jt] = 0.f; c1v[jt] = 0.f; }
  }
  const int nn = wid * 16 + l15;
  float b2v = 0, a2v = 0, c2v = 0;
  if (MODE > 0) b2v = b2[nn];
  if (MODE == 2) { a2v = a2[nn]; c2v = b2c[nn]; }

  float ss[2] = {0, 0}, qq[2] = {0, 0};   // MODE0
  float s2a = 0, q2a = 0;                 // MODE1

  for (int tile = blockIdx.x; tile < NT; tile += gridDim.x) {
    const int r0 = tile * 64;
    const int b0 = r0 / GG;
    const int g0 = r0 - b0 * GG;
    const int rem = GG - g0;   // rows before g wraps (tile wraps at most once)

    // ---- stage z tile (affine+relu+bf16, swizzled) ----
    #pragma unroll
    for (int it = 0; it < 2; ++it) {
      int sid = tid + it * 256;
      int rloc = sid >> 3;
      int g = g0 + rloc, bb = b0;
      if (rloc >= rem) { g -= GG; bb++; }
      const float4 x0 = *(const float4*)(&base[g * 64 + s * 8]);
      const float4 x1 = *(const float4*)(&base[g * 64 + s * 8 + 4]);
      const float4 f0 = *(const float4*)(&fused[bb * 64 + s * 8]);
      const float4 f1 = *(const float4*)(&fused[bb * 64 + s * 8 + 4]);
      union { short8 v; ushort u[8]; } pk;
      pk.u[0] = f2b(fmaxf(fmaf(azv0.x, x0.x + f0.x, bzv0.x), 0.f));
      pk.u[1] = f2b(fmaxf(fmaf(azv0.y, x0.y + f0.y, bzv0.y), 0.f));
      pk.u[2] = f2b(fmaxf(fmaf(azv0.z, x0.z + f0.z, bzv0.z), 0.f));
      pk.u[3] = f2b(fmaxf(fmaf(azv0.w, x0.w + f0.w, bzv0.w), 0.f));
      pk.u[4] = f2b(fmaxf(fmaf(azv1.x, x1.x + f1.x, bzv1.x), 0.f));
      pk.u[5] = f2b(fmaxf(fmaf(azv1.y, x1.y + f1.y, bzv1.y), 0.f));
      pk.u[6] = f2b(fmaxf(fmaf(azv1.z, x1.z + f1.z, bzv1.z), 0.f));
      pk.u[7] = f2b(fmaxf(fmaf(azv1.w, x1.w + f1.w, bzv1.w), 0.f));
      *(short8*)(smz + rloc * 128 + ((s ^ (rloc & 7)) << 4)) = pk.v;
    }
    if (MODE == 2) {
      int rloc = tid >> 2, c0 = (tid & 3) * 16;
      int g = g0 + rloc; if (rloc >= rem) g -= GG;
      #pragma unroll
      for (int i = 0; i < 4; ++i)
        *(float4*)(&smiw[rloc * 68 + c0 + 4 * i]) = *(const float4*)(&iw1[g * 64 + c0 + 4 * i]);
    }
    __syncthreads();   // (A)

    // ---- GEMM1: D1[rt][jt] ----
    f32x4 d1[4][2];
    #pragma unroll
    for (int rt = 0; rt < 4; ++rt)
      #pragma unroll
      for (int jt = 0; jt < 2; ++jt) d1[rt][jt] = (f32x4){0.f, 0.f, 0.f, 0.f};
    #pragma unroll
    for (int ks = 0; ks < 2; ++ks) {
      short8 af[4];
      #pragma unroll
      for (int rt = 0; rt < 4; ++rt) {
        int r = 16 * rt + l15;
        af[rt] = *(short8*)(smz + r * 128 + (((l4 + 4 * ks) ^ (l15 & 7)) << 4));
      }
      #pragma unroll
      for (int jt = 0; jt < 2; ++jt)
        #pragma unroll
        for (int rt = 0; rt < 4; ++rt)
          d1[rt][jt] = __builtin_amdgcn_mfma_f32_16x16x32_bf16(af[rt], b1f[jt][ks], d1[rt][jt], 0, 0, 0);
    }

    if (MODE == 0) {
      #pragma unroll
      for (int rt = 0; rt < 4; ++rt)
        #pragma unroll
        for (int jt = 0; jt < 2; ++jt)
          #pragma unroll
          for (int reg = 0; reg < 4; ++reg) {
            float y = d1[rt][jt][reg] + b1v[jt];
            ss[jt] += y; qq[jt] += y * y;
          }
      __syncthreads();   // guard next z-stage vs this GEMM1's reads
    } else {
      // ---- epilogue1: t = relu(a1*y1+b1c) -> LDS bf16 (swizzled) ----
      #pragma unroll
      for (int rt = 0; rt < 4; ++rt)
        #pragma unroll
        for (int jt = 0; jt < 2; ++jt) {
          int j = wid * 32 + jt * 16 + l15;
          int jhi = j >> 3, jlo = j & 7;
          #pragma unroll
          for (int reg = 0; reg < 4; ++reg) {
            int r = 16 * rt + l4 * 4 + reg;
            float y = d1[rt][jt][reg] + b1v[jt];
            float tv = fmaxf(fmaf(a1v[jt], y, c1v[jt]), 0.f);
            *(ushort*)(smt + r * 256 + ((jhi ^ (r & 15)) << 4) + jlo * 2) = f2b(tv);
          }
        }
      __syncthreads();   // (B)

      // ---- GEMM2: D2[rt], cols n = wid*16+l15 ----
      f32x4 d2[4];
      #pragma unroll
      for (int rt = 0; rt < 4; ++rt) d2[rt] = (f32x4){0.f, 0.f, 0.f, 0.f};
      #pragma unroll
      for (int ks = 0; ks < 4; ++ks) {
        short8 af[4];
        #pragma unroll
        for (int rt = 0; rt < 4; ++rt) {
          int r = 16 * rt + l15;
          af[rt] = *(short8*)(smt + r * 256 + (((l4 + 4 * ks) ^ l15) << 4));
        }
        #pragma unroll
        for (int rt = 0; rt < 4; ++rt)
          d2[rt] = __builtin_amdgcn_mfma_f32_16x16x32_bf16(af[rt], b2f[ks], d2[rt], 0, 0, 0);
      }

      if (MODE == 1) {
        #pragma unroll
        for (int rt = 0; rt < 4; ++rt)
          #pragma unroll
          for (int reg = 0; reg < 4; ++reg) {
            float y2 = d2[rt][reg] + b2v;
            s2a += y2; q2a += y2 * y2;
          }
      } else {  // MODE 2: per-gene head
        float pa[4][4];
        #pragma unroll
        for (int rt = 0; rt < 4; ++rt)
          #pragma unroll
          for (int reg = 0; reg < 4; ++reg) {
            int r = 16 * rt + l4 * 4 + reg;
            float o = fmaf(a2v, d2[rt][reg] + b2v, c2v);
            pa[rt][reg] = o * smiw[r * 68 + nn];
          }
        #pragma unroll
        for (int m = 1; m < 16; m <<= 1)
          #pragma unroll
          for (int rt = 0; rt < 4; ++rt)
            #pragma unroll
            for (int reg = 0; reg < 4; ++reg)
              pa[rt][reg] += __shfl_xor(pa[rt][reg], m);
        if (l15 == 0) {
          #pragma unroll
          for (int rt = 0; rt < 4; ++rt)
            #pragma unroll
            for (int reg = 0; reg < 4; ++reg)
              smwp[wid * 64 + 16 * rt + l4 * 4 + reg] = pa[rt][reg];
        }
        __syncthreads();   // (C)
        if (tid < 64) {
          int g = g0 + tid; if (tid >= rem) g -= GG;
          w_out[r0 + tid] = smwp[tid] + smwp[64 + tid] + smwp[128 + tid] + smwp[192 + tid] + ib1[g];
        }
      }
    }
  }

  // ---- flush stats ----
  if (MODE == 0) {
    #pragma unroll
    for (int jt = 0; jt < 2; ++jt) {
      float a = ss[jt], q = qq[jt];
      a += __shfl_xor(a, 16); a += __shfl_xor(a, 32);
      q += __shfl_xor(q, 16); q += __shfl_xor(q, 32);
      if (l4 == 0) {
        atomicAdd(&S1[wid * 32 + jt * 16 + l15], a);
        atomicAdd(&Q1[wid * 32 + jt * 16 + l15], q);
      }
    }
  }
  if (MODE == 1) {
    float a = s2a, q = q2a;
    a += __shfl_xor(a, 16); a += __shfl_xor(a, 32);
    q += __shfl_xor(q, 16); q += __shfl_xor(q, 32);
    if (l4 == 0) {
      atomicAdd(&S2[nn], a);
      atomicAdd(&Q2[nn], q);
    }
  }
}

// ---------- launcher ----------

extern "C" void kernel_launch(void* const* d_in, const int* in_sizes, int n_in,
                              void* d_out, int out_size, void* d_ws, size_t ws_size,
                              hipStream_t stream) {
  const float* expr     = (const float*)d_in[0];
  const int*   pert     = (const int*)d_in[1];
  const int*   ei       = (const int*)d_in[2];
  const float* ew       = (const float*)d_in[3];
  const float* gene_emb = (const float*)d_in[4];
  const float* pert_emb = (const float*)d_in[5];
  const float* bn_emb_g = (const float*)d_in[6];
  const float* bn_emb_b = (const float*)d_in[7];
  const float* sg_W     = (const float*)d_in[8];
  const float* sg_b     = (const float*)d_in[9];
  const float* pf_W1    = (const float*)d_in[10];
  const float* pf_b1    = (const float*)d_in[11];
  const float* pf_g1    = (const float*)d_in[12];
  const float* pf_be1   = (const float*)d_in[13];
  const float* pf_W2    = (const float*)d_in[14];
  const float* pf_b2    = (const float*)d_in[15];
  const float* pf_g2    = (const float*)d_in[16];
  const float* pf_be2   = (const float*)d_in[17];
  const float* bnp_g    = (const float*)d_in[18];
  const float* bnp_b    = (const float*)d_in[19];
  const float* r_W1     = (const float*)d_in[20];
  const float* r_b1     = (const float*)d_in[21];
  const float* r_g1     = (const float*)d_in[22];
  const float* r_be1    = (const float*)d_in[23];
  const float* r_W2     = (const float*)d_in[24];
  const float* r_b2     = (const float*)d_in[25];
  const float* r_g2     = (const float*)d_in[26];
  const float* r_be2    = (const float*)d_in[27];
  const float* iw1      = (const float*)d_in[28];
  const float* ib1      = (const float*)d_in[29];
  const float* c_W1     = (const float*)d_in[30];
  const float* c_b1     = (const float*)d_in[31];
  const float* c_g1     = (const float*)d_in[32];
  const float* c_be1    = (const float*)d_in[33];
  const float* c_W2     = (const float*)d_in[34];
  const float* c_b2     = (const float*)d_in[35];
  const float* c_g2     = (const float*)d_in[36];
  const float* c_be2    = (const float*)d_in[37];
  const float* iw2      = (const float*)d_in[38];
  const float* ib2      = (const float*)d_in[39];
  float* out = (float*)d_out;
  float* ws = (float*)d_ws;

  float* base = ws + 0;        // [G,H]
  float* rnp  = ws + 320000;   // [G,H]
  float* agg  = ws + 640000;   // [G,H]
  float* pge  = ws + 960000;   // [G,H]
  float* wv   = ws + 1280000;  // [B,G]
  // zeroed region [1920000, 1929472)
  float* psum   = ws + 1920000;  // [B,H] (atomic accum)
  float* SQ     = ws + 1928192;  // 14 x 64 stat accumulators
  float* S_emb1 = SQ;        float* Q_emb1 = SQ + 64;
  float* S_emb2 = SQ + 128;  float* Q_emb2 = SQ + 192;
  float* S_f    = SQ + 256;  float* Q_f    = SQ + 320;
  float* S_pf1  = SQ + 384;  float* Q_pf1  = SQ + 448;
  float* S_pf2  = SQ + 512;  float* Q_pf2  = SQ + 576;
  float* S_c1   = SQ + 640;  float* Q_c1   = SQ + 704;
  float* S_c2   = SQ + 768;  float* Q_c2   = SQ + 832;
  float* S1   = ws + 1929088;  // [128]
  float* Q1   = ws + 1929216;  // [128]
  float* S2   = ws + 1929344;  // [64]
  float* Q2   = ws + 1929408;  // [64]
  // scratch
  float* fusd = ws + 1929472;  // [B,H]
  float* tmpA = ws + 1937664;  // [B,H]
  float* crs  = ws + 1945856;  // [B,H]
  float* dis  = ws + 1954048;  // [G]
  float* affa = ws + 1959048;  // [128]
  float* affb = ws + 1959176;  // [128]
  float* az   = ws + 1959304;  // [64]
  float* bz   = ws + 1959368;  // [64]
  float* a1   = ws + 1959432;  // [128]
  float* b1c  = ws + 1959560;  // [128]
  float* a2   = ws + 1959688;  // [64]
  float* b2c  = ws + 1959752;  // [64]

  const int* src = ei;
  const int* dst = ei + EE;

  // zero all atomic accumulators (psum + stats) in one shot
  hipMemsetAsync(ws + 1920000, 0, 9472 * sizeof(float), stream);
  hipMemsetAsync(dis, 0, GG * sizeof(float), stream);

  // --- gene embedding path
  renorm_rows<<<(GG + 3) / 4, 256, 0, stream>>>(gene_emb, base, GG);
  colsum<<<80, 256, 0, stream>>>(base, GG, S_emb1, Q_emb1);
  finish_bn<<<1, 64, 0, stream>>>(S_emb1, Q_emb1, bn_emb_g, bn_emb_b, affa, affb, HH, 1.0f / (float)GG);
  apply_affine<<<(GG * HH + 255) / 256, 256, 0, stream>>>(base, affa, affb, base, GG * HH, 1);
  colsum<<<80, 256, 0, stream>>>(base, GG, S_emb2, Q_emb2);

  // --- SGConv path
  renorm_rows<<<(GG + 3) / 4, 256, 0, stream>>>(pert_emb, rnp, GG);
  edge_deg<<<(EE + 255) / 256, 256, 0, stream>>>(dst, ew, dis);
  finish_dis<<<(GG + 255) / 256, 256, 0, stream>>>(dis);
  agg_init<<<(GG * HH + 255) / 256, 256, 0, stream>>>(dis, rnp, agg);
  agg_edges<<<(EE * 64 + 255) / 256, 256, 0, stream>>>(src, dst, ew, dis, rnp, agg);
  gemm_rows64<<<(GG + 3) / 4, 256, 0, stream>>>(agg, sg_W, sg_b, pge, GG, HH);
  psum_kernel<<<dim3(BB, 10), 256, 0, stream>>>(pert, pge, psum);

  // --- pert_fuse MLP
  gemm_rows64<<<(BB + 3) / 4, 256, 0, stream>>>(psum, pf_W1, pf_b1, tmpA, BB, HH);
  colsum<<<32, 256, 0, stream>>>(tmpA, BB, S_pf1, Q_pf1);
  finish_bn<<<1, 64, 0, stream>>>(S_pf1, Q_pf1, pf_g1, pf_be1, affa, affb, HH, 1.0f / (float)BB);
  apply_affine<<<(BB * HH + 255) / 256, 256, 0, stream>>>(tmpA, affa, affb, tmpA, BB * HH, 1);
  gemm_rows64<<<(BB + 3) / 4, 256, 0, stream>>>(tmpA, pf_W2, pf_b2, fusd, BB, HH);
  colsum<<<32, 256, 0, stream>>>(fusd, BB, S_pf2, Q_pf2);
  finish_bn<<<1, 64, 0, stream>>>(S_pf2, Q_pf2, pf_g2, pf_be2, affa, affb, HH, 1.0f / (float)BB);
  apply_affine<<<(BB * HH + 255) / 256, 256, 0, stream>>>(fusd, affa, affb, fusd, BB * HH, 0);
  colsum<<<32, 256, 0, stream>>>(fusd, BB, S_f, Q_f);
  make_bnp<<<1, 64, 0, stream>>>(S_emb2, Q_emb2, S_f, Q_f, bnp_g, bnp_b, az, bz);

  // --- recovery MLP over 640K rows (3 MFMA passes)
  big_kernel<0><<<768, 256, 0, stream>>>(base, fusd, az, bz, r_W1, r_b1, r_W2, r_b2,
                                         a1, b1c, a2, b2c, iw1, ib1, S1, Q1, S2, Q2, wv);
  finish_bn<<<1, 128, 0, stream>>>(S1, Q1, r_g1, r_be1, a1, b1c, 128, 1.0f / (float)RR);
  big_kernel<1><<<768, 256, 0, stream>>>(base, fusd, az, bz, r_W1, r_b1, r_W2, r_b2,
                                         a1, b1c, a2, b2c, iw1, ib1, S1, Q1, S2, Q2, wv);
  finish_bn<<<1, 64, 0, stream>>>(S2, Q2, r_g2, r_be2, a2, b2c, 64, 1.0f / (float)RR);
  big_kernel<2><<<768, 256, 0, stream>>>(base, fusd, az, bz, r_W1, r_b1, r_W2, r_b2,
                                         a1, b1c, a2, b2c, iw1, ib1, S1, Q1, S2, Q2, wv);

  // --- cross_gene_state MLP
  cross1_kernel<<<2048, 256, 0, stream>>>(wv, c_W1, c_b1, tmpA);
  colsum<<<32, 256, 0, stream>>>(tmpA, BB, S_c1, Q_c1);
  finish_bn<<<1, 64, 0, stream>>>(S_c1, Q_c1, c_g1, c_be1, affa, affb, HH, 1.0f / (float)BB);
  apply_affine<<<(BB * HH + 255) / 256, 256, 0, stream>>>(tmpA, affa, affb, tmpA, BB * HH, 1);
  gemm_rows64<<<(BB + 3) / 4, 256, 0, stream>>>(tmpA, c_W2, c_b2, crs, BB, HH);
  colsum<<<32, 256, 0, stream>>>(crs, BB, S_c2, Q_c2);
  finish_bn<<<1, 64, 0, stream>>>(S_c2, Q_c2, c_g2, c_be2, affa, affb, HH, 1.0f / (float)BB);
  apply_affine<<<(BB * HH + 255) / 256, 256, 0, stream>>>(crs, affa, affb, crs, BB * HH, 0);

  // --- final per-gene head + residual
  final_kernel<<<dim3((GG + 255) / 256, BB / 16), 256, 0, stream>>>(wv, crs, iw2, ib2, expr, out);
}